// Round 12
// baseline (187.342 us; speedup 1.0000x reference)
//
#include <hip/hip_runtime.h>
#include <hip/hip_bf16.h>
#include <math.h>
#include <stdint.h>

#define BATCH 2
#define SEQ 1024
#define HIDDIM 2048
#define NH 8
#define DKD 64
#define DVD 128
#define TKD 512
#define TVD 1024
#define NCOL 3088   // TK+TK+TV+H+H+TV
#define KSZ 4
#define NCHK 16

typedef __attribute__((ext_vector_type(8))) short bf16x8;
typedef __attribute__((ext_vector_type(4))) float f32x4;
typedef __attribute__((ext_vector_type(16))) float f32x16;

__device__ __forceinline__ float sigm(float x){ return 1.f/(1.f+expf(-x)); }
__device__ __forceinline__ float siluf(float x){ return x/(1.f+expf(-x)); }
__device__ __forceinline__ float b2f(unsigned short u){
  union { unsigned int i; float f; } x; x.i = ((unsigned int)u) << 16; return x.f;
}
__device__ __forceinline__ unsigned short f2bu(float f){
  __hip_bfloat16 h = __float2bfloat16(f);
  return *(unsigned short*)&h;
}

__device__ __forceinline__ void glds16(const __hip_bfloat16* g, void* l) {
  __builtin_amdgcn_global_load_lds((const __attribute__((address_space(1))) void*)g,
                                   (__attribute__((address_space(3))) void*)l, 16, 0, 0);
}

// ---------------- fused prep: 4 transposing casts + hidden cast -------------
__global__ __launch_bounds__(256) void prep_k(
    const float* __restrict__ Wqkvabz, const float* __restrict__ w1,
    const float* __restrict__ w2, const float* __restrict__ W_o,
    const float* __restrict__ hidden,
    __hip_bfloat16* __restrict__ Wcat, __hip_bfloat16* __restrict__ w2t,
    __hip_bfloat16* __restrict__ Wot, unsigned short* __restrict__ hidden_bf)
{
  __shared__ float tile[32][33];
  const int blk = blockIdx.x;
  const float* in; __hip_bfloat16* out; int R, C, bx, by;
  if (blk < 6400)      { in=Wqkvabz; out=Wcat; R=2048; C=3088; bx=blk%100; by=blk/100; }
  else if (blk < 6656) { int t=blk-6400; in=w1;  out=Wcat+(size_t)3200*2048; R=2048; C=128;  bx=t%4;   by=t/4; }
  else if (blk < 7168) { int t=blk-6656; in=w2;  out=w2t; R=128;  C=4096; bx=t%128; by=t/128; }
  else if (blk < 9216) { int t=blk-7168; in=W_o; out=Wot; R=1024; C=2048; bx=t%64;  by=t/64; }
  else {
    int i = (blk - 9216)*256 + threadIdx.x;
    float4 v = ((const float4*)hidden)[i];
    ushort4 o; o.x=f2bu(v.x); o.y=f2bu(v.y); o.z=f2bu(v.z); o.w=f2bu(v.w);
    ((ushort4*)hidden_bf)[i] = o;
    return;
  }
  const int tx = threadIdx.x & 31, ty = threadIdx.x >> 5;
  const int c = bx*32 + tx;
  #pragma unroll
  for (int i = 0; i < 4; ++i) {
    int r = by*32 + ty + i*8;
    tile[ty + i*8][tx] = (c < C) ? in[(size_t)r*C + c] : 0.f;
  }
  __syncthreads();
  #pragma unroll
  for (int i = 0; i < 4; ++i) {
    int orow = bx*32 + ty + i*8;
    int ocol = by*32 + tx;
    out[(size_t)orow*R + ocol] = __float2bfloat16(tile[tx][ty + i*8]);
  }
}

// ---------------- bf16 MFMA GEMM, 32x32x16 frags, BM=128 x BN=128 ----------
// C = A[M][K] @ Bt[N][K]^T ; 1D grid + XCD swizzle; depth-2 counted vmcnt.
// 4 waves (2x2), wave-tile 64x64, 2x2 frags of 32x32, acc f32x16 each.
// LDS tile [128 rows][32 k] bf16, 4 slots of 16B per row; swizzle slot^=(row&3)
// (pre-swizzled global source; glds dest linear). Frag reads conflict-free.
// EPI: 0 = fp32 out; 2 = +bias -> bf16; 3 = fused qkvabz(+z bf16)+w1
template<int EPI>
__global__ __launch_bounds__(256) void mgemm_k(
    const __hip_bfloat16* __restrict__ A,
    const __hip_bfloat16* __restrict__ Bt,
    const float* __restrict__ bias,
    float* __restrict__ Cf, __hip_bfloat16* __restrict__ Cb,
    unsigned short* __restrict__ Zb,
    int M, int N, int K, int nbx)
{
  __shared__ __hip_bfloat16 As[2][128*32];
  __shared__ __hip_bfloat16 Bs[2][128*32];
  const int tid = threadIdx.x;
  const int w = tid >> 6, l = tid & 63;
  const int wr = w >> 1, wc = w & 1;
  const int nwg = gridDim.x, q = nwg >> 3;
  const int swz = (blockIdx.x & 7)*q + (blockIdx.x >> 3);
  const int bx = swz % nbx, by = swz / nbx;
  const int row0 = by*128, col0 = bx*128;

  f32x16 acc[2][2];
  #pragma unroll
  for (int mi = 0; mi < 2; ++mi)
    #pragma unroll
    for (int ni = 0; ni < 2; ++ni)
      #pragma unroll
      for (int r = 0; r < 16; ++r)
        acc[mi][ni][r] = 0.f;

  // staging: lane l -> LDS rows {ra, ra+64}, slot (l&3); pre-swizzled source
  const int ra = w*16 + (l >> 2);
  const int sg = (l & 3) ^ ((l >> 2) & 3);

  const __hip_bfloat16* pA0 = &A[(size_t)(row0 + ra)*K + sg*8];
  const __hip_bfloat16* pA1 = &A[(size_t)(row0 + ra + 64)*K + sg*8];
  const __hip_bfloat16* pB0 = &Bt[(size_t)(col0 + ra)*K + sg*8];
  const __hip_bfloat16* pB1 = &Bt[(size_t)(col0 + ra + 64)*K + sg*8];

  // prologue: stage tiles 0 and 1 (8 loads in flight per wave)
  glds16(pA0,      (char*)&As[0][0] + w*1024);
  glds16(pA1,      (char*)&As[0][0] + 4096 + w*1024);
  glds16(pB0,      (char*)&Bs[0][0] + w*1024);
  glds16(pB1,      (char*)&Bs[0][0] + 4096 + w*1024);
  if (K > 32) {
    glds16(pA0 + 32, (char*)&As[1][0] + w*1024);
    glds16(pA1 + 32, (char*)&As[1][0] + 4096 + w*1024);
    glds16(pB0 + 32, (char*)&Bs[1][0] + w*1024);
    glds16(pB1 + 32, (char*)&Bs[1][0] + 4096 + w*1024);
  }

  int cur = 0;
  for (int k0 = 0; k0 < K; k0 += 32) {
    if (k0 + 32 < K) asm volatile("s_waitcnt vmcnt(4)" ::: "memory");
    else             asm volatile("s_waitcnt vmcnt(0)" ::: "memory");
    __builtin_amdgcn_s_barrier();

    #pragma unroll
    for (int ks = 0; ks < 2; ++ks) {
      bf16x8 af[2], bfv[2];
      #pragma unroll
      for (int mi = 0; mi < 2; ++mi) {
        const int ar = wr*64 + mi*32 + (l & 31);
        af[mi] = *(const bf16x8*)&As[cur][ar*32 + (((ks*2 + (l>>5)) ^ (ar&3)))*8];
      }
      #pragma unroll
      for (int ni = 0; ni < 2; ++ni) {
        const int br = wc*64 + ni*32 + (l & 31);
        bfv[ni] = *(const bf16x8*)&Bs[cur][br*32 + (((ks*2 + (l>>5)) ^ (br&3)))*8];
      }
      #pragma unroll
      for (int mi = 0; mi < 2; ++mi)
        #pragma unroll
        for (int ni = 0; ni < 2; ++ni)
          acc[mi][ni] = __builtin_amdgcn_mfma_f32_32x32x16_bf16(af[mi], bfv[ni], acc[mi][ni], 0, 0, 0);
    }

    __builtin_amdgcn_s_barrier();   // all waves done reading buf[cur]
    if (k0 + 64 < K) {              // stage tile k+2 into the freed buffer
      glds16(pA0 + k0 + 64, (char*)&As[cur][0] + w*1024);
      glds16(pA1 + k0 + 64, (char*)&As[cur][0] + 4096 + w*1024);
      glds16(pB0 + k0 + 64, (char*)&Bs[cur][0] + w*1024);
      glds16(pB1 + k0 + 64, (char*)&Bs[cur][0] + 4096 + w*1024);
    }
    cur ^= 1;
  }

  // epilogue: D col = lane&31, row = (reg&3) + 8*(reg>>2) + 4*(lane>>5)
  #pragma unroll
  for (int mi = 0; mi < 2; ++mi) {
    #pragma unroll
    for (int ni = 0; ni < 2; ++ni) {
      const int ccol = col0 + wc*64 + ni*32 + (l & 31);
      #pragma unroll
      for (int r = 0; r < 16; ++r) {
        const int crow = row0 + wr*64 + mi*32 + (r&3) + 8*(r>>2) + 4*(l>>5);
        float v = acc[mi][ni][r];
        if (EPI == 0) {
          Cf[(size_t)crow*N + ccol] = v;
        } else if (EPI == 2) {
          Cb[(size_t)crow*N + ccol] = __float2bfloat16(v + bias[ccol]);
        } else { // EPI == 3
          if (ccol < 2064)       Cf[(size_t)crow*NCOL + ccol] = v;
          else if (ccol < 3088)  Zb[(size_t)crow*1024 + (ccol - 2064)] = f2bu(v);
          else if (ccol >= 3200) Cb[(size_t)crow*128 + (ccol - 3200)] = __float2bfloat16(siluf(v));
        }
      }
    }
  }
}

// ---------------- fused actv (silu+l2norm q/k, g, beta) + dynamic conv -----
__global__ __launch_bounds__(256) void ac_k(const float* __restrict__ qkvabz,
    const float* __restrict__ A_log, const float* __restrict__ dt_bias,
    const __hip_bfloat16* __restrict__ kern, const float* __restrict__ conv_state,
    float* __restrict__ kn, unsigned short* __restrict__ qnb,
    unsigned short* __restrict__ knb,
    float* __restrict__ g, float* __restrict__ beta, float* __restrict__ vconv)
{
  if (blockIdx.x < 4096) {
    int gid = blockIdx.x*4 + (threadIdx.x >> 6);
    int lane = threadIdx.x & 63;
    int row = gid >> 3; int h = gid & 7;
    const float* base = qkvabz + (size_t)row * NCOL;
    float qv = base[h*64 + lane];
    float kv = base[TKD + h*64 + lane];
    float sq = siluf(qv), sk = siluf(kv);
    float ssq = sq*sq, ssk = sk*sk;
    #pragma unroll
    for (int o = 32; o; o >>= 1) { ssq += __shfl_xor(ssq, o); ssk += __shfl_xor(ssk, o); }
    float qn_v = sq * rsqrtf(ssq + 1e-6f) * 0.125f;
    float kn_v = sk * rsqrtf(ssk + 1e-6f);
    size_t idx = (size_t)row*TKD + h*64 + lane;
    kn[idx]  = kn_v;
    qnb[idx] = f2bu(qn_v);
    knb[idx] = f2bu(kn_v);
    if (lane == 0) {
      float av = base[2048 + h] + dt_bias[h];
      float sp = fmaxf(av, 0.f) + log1pf(expf(-fabsf(av)));
      g[(size_t)row*NH + h] = -expf(A_log[h]) * sp;
      float bv = base[2056 + h];
      beta[(size_t)row*NH + h] = sigm(bv);
    }
  } else {
    int idx = (blockIdx.x - 4096)*256 + threadIdx.x;
    int c = idx & (TVD-1);
    int bs = idx >> 10;
    int s = bs & (SEQ-1); int b = bs >> 10;
    ushort4 kf = *(const ushort4*)&kern[(size_t)idx * 4];
    float kj[4] = { b2f(kf.x), b2f(kf.y), b2f(kf.z), b2f(kf.w) };
    float acc = 0.f;
    #pragma unroll
    for (int j = 0; j < 4; ++j) {
      int i = s + j;
      float xv = (i < 3) ? conv_state[((size_t)b*TVD + c)*3 + i]
                         : qkvabz[((size_t)(b*SEQ + (i-3)))*NCOL + TKD*2 + c];
      acc = fmaf(xv, kj[j], acc);
    }
    vconv[idx] = siluf(acc);
  }
}

// ============ chunked gated delta rule =====================================
// Phase A: MFMA A-build + register-column trisolve + fp32 D/b
__global__ __launch_bounds__(256) void chunkA_k(const float* __restrict__ kn,
   const unsigned short* __restrict__ knb,
   const float* __restrict__ vconv, const float* __restrict__ gb,
   const float* __restrict__ bb, float* __restrict__ Gcbuf,
   float* __restrict__ Dbuf, float* __restrict__ Bvec,
   unsigned short* __restrict__ UvT, unsigned short* __restrict__ WnTb)
{
  const int blk = blockIdx.x;
  const int bh = blk >> 4, c = blk & 15;
  const int b = bh >> 3, h = bh & 7;
  const int tid = threadIdx.x;
  const int w = tid >> 6, l = tid & 63;
  const int fr = l & 15, fq = l >> 4;
  const int row0 = b*SEQ + c*64;

  __shared__ unsigned short Kb[64*72];
  __shared__ float Xv[64][132];
  __shared__ float Xw[64][68];
  __shared__ float AK[64][68];
  __shared__ float Gsh[64], Bsh[64];

  #pragma unroll
  for (int j = 0; j < 2; ++j) {
    int lin = tid + j*256; int t = lin >> 3, dq = (lin & 7)*8;
    *(uint4*)&Kb[t*72+dq] = *(const uint4*)&knb[(size_t)(row0+t)*TKD + h*64 + dq];
  }
  #pragma unroll
  for (int i = 0; i < 8; ++i) {
    int lin = tid + i*256; int t = lin >> 5, v4 = (lin & 31)*4;
    float4 vv = *(const float4*)&vconv[(size_t)(row0+t)*TVD + h*128 + v4];
    Xv[t][v4]=vv.x; Xv[t][v4+1]=vv.y; Xv[t][v4+2]=vv.z; Xv[t][v4+3]=vv.w;
  }
  if (tid < 64) {
    float gv = gb[(size_t)(row0+tid)*NH + h];
    #pragma unroll
    for (int o = 1; o < 64; o <<= 1) {
      float oth = __shfl_up(gv, o);
      if (tid >= o) gv += oth;
    }
    Gsh[tid] = gv;
    Bsh[tid] = bb[(size_t)(row0+tid)*NH + h];
    Gcbuf[(size_t)blk*64 + tid] = gv;
  }
  __syncthreads();

  {
    f32x4 accS[4];
    #pragma unroll
    for (int n = 0; n < 4; ++n) accS[n] = (f32x4){0.f,0.f,0.f,0.f};
    #pragma unroll
    for (int k0 = 0; k0 < 2; ++k0) {
      bf16x8 a = *(const bf16x8*)&Kb[(w*16+fr)*72 + k0*32 + fq*8];
      #pragma unroll
      for (int n = 0; n < 4; ++n) {
        bf16x8 bb2 = *(const bf16x8*)&Kb[(n*16+fr)*72 + k0*32 + fq*8];
        accS[n] = __builtin_amdgcn_mfma_f32_16x16x32_bf16(a, bb2, accS[n], 0, 0, 0);
      }
    }
    #pragma unroll
    for (int n = 0; n < 4; ++n)
      #pragma unroll
      for (int r = 0; r < 4; ++r) {
        int t = w*16 + fq*4 + r, s = n*16 + fr;
        AK[t][s] = (s < t) ? Bsh[t]*expf(Gsh[t]-Gsh[s])*accS[n][r] : 0.f;
      }
  }
  #pragma unroll
  for (int i = 0; i < 4; ++i) {
    int lin = tid + i*256; int t = lin >> 4, d4 = (lin & 15)*4;
    float4 kv = *(const float4*)&kn[(size_t)(row0+t)*TKD + h*64 + d4];
    float f = Bsh[t]*expf(Gsh[t]);
    Xw[t][d4+0]=f*kv.x; Xw[t][d4+1]=f*kv.y; Xw[t][d4+2]=f*kv.z; Xw[t][d4+3]=f*kv.w;
  }
  __syncthreads();

  if (tid < 192) {
    float x[64];
    if (tid < 128) {
      #pragma unroll
      for (int t = 0; t < 64; ++t) x[t] = Bsh[t]*Xv[t][tid];
    } else {
      #pragma unroll
      for (int t = 0; t < 64; ++t) x[t] = Xw[t][tid-128];
    }
    #pragma unroll
    for (int t = 1; t < 64; ++t) {
      float a0=0.f, a1=0.f, a2=0.f, a3=0.f;
      #pragma unroll
      for (int s4 = 0; s4 < (t+3)/4; ++s4) {
        float4 av = *(const float4*)&AK[t][s4*4];
        a0 = fmaf(av.x, x[s4*4+0], a0);
        a1 = fmaf(av.y, x[s4*4+1], a1);
        a2 = fmaf(av.z, x[s4*4+2], a2);
        a3 = fmaf(av.w, x[s4*4+3], a3);
      }
      x[t] -= (a0+a1)+(a2+a3);
    }
    if (tid < 128) {
      #pragma unroll
      for (int t = 0; t < 64; ++t) Xv[t][tid] = x[t];
    } else {
      #pragma unroll
      for (int t = 0; t < 64; ++t) Xw[t][tid-128] = x[t];
    }
  }
  __syncthreads();

  const float Gtot = Gsh[63];
  #pragma unroll
  for (int i = 0; i < 4; ++i) {
    int lin = tid + i*256; int t = lin >> 4, d4 = (lin & 15)*4;
    float4 kv = *(const float4*)&kn[(size_t)(row0+t)*TKD + h*64 + d4];
    float f = expf(Gtot - Gsh[t]);
    AK[t][d4+0]=f*kv.x; AK[t][d4+1]=f*kv.y; AK[t][d4+2]=f*kv.z; AK[t][d4+3]=f*kv.w;
  }
  __syncthreads();

  {
    const int d1b = (tid >> 4)*4, d2b = (tid & 15)*4;
    float dacc[4][4] = {};
    #pragma unroll 8
    for (int t = 0; t < 64; ++t) {
      float4 kw = *(const float4*)&AK[t][d1b];
      float4 wv = *(const float4*)&Xw[t][d2b];
      float kwa[4] = {kw.x,kw.y,kw.z,kw.w};
      float wva[4] = {wv.x,wv.y,wv.z,wv.w};
      #pragma unroll
      for (int i = 0; i < 4; ++i)
        #pragma unroll
        for (int j = 0; j < 4; ++j)
          dacc[i][j] = fmaf(kwa[i], wva[j], dacc[i][j]);
    }
    const float eG = expf(Gtot);
    #pragma unroll
    for (int i = 0; i < 4; ++i) {
      float vals[4];
      #pragma unroll
      for (int j = 0; j < 4; ++j) {
        float v = -dacc[i][j];
        if (d1b + i == d2b + j) v += eG;
        vals[j] = v;
      }
      *(float4*)&Dbuf[(size_t)blk*4096 + (d1b+i)*64 + d2b] =
        make_float4(vals[0],vals[1],vals[2],vals[3]);
    }
  }
  {
    const int d1b = (tid >> 4)*4, vb = (tid & 15)*8;
    float bacc[4][8] = {};
    #pragma unroll 4
    for (int t = 0; t < 64; ++t) {
      float4 kw = *(const float4*)&AK[t][d1b];
      float4 u0 = *(const float4*)&Xv[t][vb];
      float4 u1 = *(const float4*)&Xv[t][vb+4];
      float kwa[4] = {kw.x,kw.y,kw.z,kw.w};
      float ua[8] = {u0.x,u0.y,u0.z,u0.w,u1.x,u1.y,u1.z,u1.w};
      #pragma unroll
      for (int i = 0; i < 4; ++i)
        #pragma unroll
        for (int j = 0; j < 8; ++j)
          bacc[i][j] = fmaf(kwa[i], ua[j], bacc[i][j]);
    }
    #pragma unroll
    for (int i = 0; i < 4; ++i) {
      *(float4*)&Bvec[(size_t)blk*8192 + (d1b+i)*128 + vb] =
        make_float4(bacc[i][0],bacc[i][1],bacc[i][2],bacc[i][3]);
      *(float4*)&Bvec[(size_t)blk*8192 + (d1b+i)*128 + vb + 4] =
        make_float4(bacc[i][4],bacc[i][5],bacc[i][6],bacc[i][7]);
    }
  }

  {
    #pragma unroll
    for (int i = 0; i < 32; ++i) {
      int v = w*32 + i;
      UvT[(size_t)blk*8192 + v*64 + l] = f2bu(Xv[l][v]);
    }
    #pragma unroll
    for (int i = 0; i < 16; ++i) {
      int d = w*16 + i;
      WnTb[(size_t)blk*4096 + d*64 + l] = f2bu(-Xw[l][d]);
    }
  }
}

// Phase B: h_{c+1} = D_c h_c + b_c ; 128 blocks (bh x 8 vgroups of 16)
__global__ __launch_bounds__(256) void chunkB2_k(const float* __restrict__ Dbuf,
   const float* __restrict__ Bvec, const float* __restrict__ init,
   unsigned short* __restrict__ HcT)
{
  const int blk = blockIdx.x;
  const int bh = blk >> 3, grp = blk & 7;
  const int v0 = grp*16;
  const int tid = threadIdx.x;
  const int v = tid & 15;
  const int d1b = (tid >> 4) * 4;
  __shared__ float DT[64][68];
  __shared__ float bsh[64][17];
  __shared__ float hsh[64][17];

  float hreg[4];
  #pragma unroll
  for (int j = 0; j < 4; ++j) {
    hreg[j] = init[((size_t)bh*64 + d1b + j)*128 + v0 + v];
    hsh[d1b + j][v] = hreg[j];
  }
  float Dreg[16], breg[4];
  {
    const float* Dp = Dbuf + (size_t)(bh*16)*4096;
    const float* bp = Bvec + (size_t)(bh*16)*8192;
    #pragma unroll
    for (int i = 0; i < 16; ++i) Dreg[i] = Dp[tid + i*256];
    #pragma unroll
    for (int i = 0; i < 4; ++i)  breg[i] = bp[(size_t)((tid>>4) + i*16)*128 + v0 + v];
  }
  #pragma unroll
  for (int i = 0; i < 16; ++i) {
    int cell = tid + i*256; DT[cell & 63][cell >> 6] = Dreg[i];
  }
  #pragma unroll
  for (int i = 0; i < 4; ++i) bsh[(tid>>4) + i*16][v] = breg[i];
  __syncthreads();

  for (int c = 0; c < 16; ++c) {
    if (c < 15) {
      const float* Dn = Dbuf + (size_t)(bh*16 + c + 1)*4096;
      const float* bn = Bvec + (size_t)(bh*16 + c + 1)*8192;
      #pragma unroll
      for (int i = 0; i < 16; ++i) Dreg[i] = Dn[tid + i*256];
      #pragma unroll
      for (int i = 0; i < 4; ++i)  breg[i] = bn[(size_t)((tid>>4) + i*16)*128 + v0 + v];
    }
    #pragma unroll
    for (int j = 0; j < 4; ++j)
      HcT[(size_t)(bh*16 + c)*8192 + (size_t)(v0+v)*64 + d1b + j] = f2bu(hreg[j]);
    float nh[4];
    #pragma unroll
    for (int j = 0; j < 4; ++j) nh[j] = bsh[d1b + j][v];
    #pragma unroll 8
    for (int d2 = 0; d2 < 64; ++d2) {
      float hv = hsh[d2][v];
      float4 dv = *(const float4*)&DT[d2][d1b];
      nh[0] = fmaf(dv.x, hv, nh[0]);
      nh[1] = fmaf(dv.y, hv, nh[1]);
      nh[2] = fmaf(dv.z, hv, nh[2]);
      nh[3] = fmaf(dv.w, hv, nh[3]);
    }
    __syncthreads();
    #pragma unroll
    for (int j = 0; j < 4; ++j) { hreg[j] = nh[j]; hsh[d1b + j][v] = nh[j]; }
    if (c < 15) {
      #pragma unroll
      for (int i = 0; i < 16; ++i) {
        int cell = tid + i*256; DT[cell & 63][cell >> 6] = Dreg[i];
      }
      #pragma unroll
      for (int i = 0; i < 4; ++i) bsh[(tid>>4) + i*16][v] = breg[i];
    }
    __syncthreads();
  }
}

// Phase C (MFMA): S = decayed-masked QK^T; Qt = E.Q - S Wt; o = Qt h + S U;
// fused gated RMSNorm -> ofin bf16
__global__ __launch_bounds__(256) void chunkC_k(
   const unsigned short* __restrict__ qnb, const unsigned short* __restrict__ knb,
   const unsigned short* __restrict__ UvT, const unsigned short* __restrict__ WnTb,
   const float* __restrict__ Gcbuf, const unsigned short* __restrict__ HcT,
   const unsigned short* __restrict__ Zb, const float* __restrict__ onw,
   __hip_bfloat16* __restrict__ ofin)
{
  const int blk = blockIdx.x; const int bh = blk >> 4, c = blk & 15;
  const int b = bh >> 3, h = bh & 7;
  const int row0 = b*SEQ + c*64;
  const int tid = threadIdx.x;
  const int w = tid >> 6, l = tid & 63;
  const int fr = l & 15, fq = l >> 4;

  __shared__ unsigned short Qs[64*72];
  __shared__ unsigned short Ks[64*72];
  __shared__ unsigned short Ws[64*72];
  __shared__ unsigned short hT[128*72];
  __shared__ unsigned short UT[128*72];
  __shared__ unsigned short Ss[64*72];
  __shared__ float Gsh[64], Esh[64];

  #pragma unroll
  for (int j = 0; j < 2; ++j) {
    int lin = tid + j*256; int t = lin >> 3, dq = (lin & 7)*8;
    *(uint4*)&Qs[t*72+dq] = *(const uint4*)&qnb[(size_t)(row0+t)*TKD + h*64 + dq];
    *(uint4*)&Ks[t*72+dq] = *(const uint4*)&knb[(size_t)(row0+t)*TKD + h*64 + dq];
    *(uint4*)&Ws[t*72+dq] = *(const uint4*)&WnTb[(size_t)blk*4096 + t*64 + dq];
  }
  #pragma unroll
  for (int j = 0; j < 4; ++j) {
    int lin = tid + j*256; int v = lin >> 3, dq = (lin & 7)*8;
    *(uint4*)&hT[v*72+dq] = *(const uint4*)&HcT[(size_t)blk*8192 + (size_t)v*64 + dq];
    *(uint4*)&UT[v*72+dq] = *(const uint4*)&UvT[(size_t)blk*8192 + (size_t)v*64 + dq];
  }
  if (tid < 64) { float g = Gcbuf[(size_t)blk*64 + tid]; Gsh[tid] = g; Esh[tid] = expf(g); }
  __syncthreads();

  f32x4 accS[4];
  #pragma unroll
  for (int n = 0; n < 4; ++n) accS[n] = (f32x4){0.f,0.f,0.f,0.f};
  #pragma unroll
  for (int k0 = 0; k0 < 2; ++k0) {
    bf16x8 a = *(const bf16x8*)&Qs[(w*16+fr)*72 + k0*32 + fq*8];
    #pragma unroll
    for (int n = 0; n < 4; ++n) {
      bf16x8 bb = *(const bf16x8*)&Ks[(n*16+fr)*72 + k0*32 + fq*8];
      accS[n] = __builtin_amdgcn_mfma_f32_16x16x32_bf16(a, bb, accS[n], 0, 0, 0);
    }
  }
  #pragma unroll
  for (int n = 0; n < 4; ++n)
    #pragma unroll
    for (int r = 0; r < 4; ++r) {
      int t = w*16 + fq*4 + r, s = n*16 + fr;
      float val = (s <= t) ? expf(Gsh[t]-Gsh[s]) * accS[n][r] : 0.f;
      Ss[t*72 + s] = f2bu(val);
    }

  f32x4 accQ[4];
  #pragma unroll
  for (int n = 0; n < 4; ++n) {
    #pragma unroll
    for (int r = 0; r < 4; ++r) {
      int t = w*16 + fq*4 + r, d = n*16 + fr;
      accQ[n][r] = Esh[t] * b2f(Qs[t*72 + d]);
    }
    #pragma unroll
    for (int k0 = 0; k0 < 2; ++k0) {
      bf16x8 a = *(const bf16x8*)&Ss[(w*16+fr)*72 + k0*32 + fq*8];
      bf16x8 bb = *(const bf16x8*)&Ws[(n*16+fr)*72 + k0*32 + fq*8];
      accQ[n] = __builtin_amdgcn_mfma_f32_16x16x32_bf16(a, bb, accQ[n], 0, 0, 0);
    }
  }
  __syncthreads();

  #pragma unroll
  for (int n = 0; n < 4; ++n)
    #pragma unroll
    for (int r = 0; r < 4; ++r) {
      int t = w*16 + fq*4 + r, d = n*16 + fr;
      Ks[t*72 + d] = f2bu(accQ[n][r]);
    }

  float og[8][4];
  #pragma unroll
  for (int n = 0; n < 8; ++n) {
    f32x4 acc = (f32x4){0.f,0.f,0.f,0.f};
    #pragma unroll
    for (int k0 = 0; k0 < 2; ++k0) {
      bf16x8 a1 = *(const bf16x8*)&Ks[(w*16+fr)*72 + k0*32 + fq*8];
      bf16x8 b1 = *(const bf16x8*)&hT[(n*16+fr)*72 + k0*32 + fq*8];
      acc = __builtin_amdgcn_mfma_f32_16x16x32_bf16(a1, b1, acc, 0, 0, 0);
      bf16x8 a2 = *(const bf16x8*)&Ss[(w*16+fr)*72 + k0*32 + fq*8];
      bf16x8 b2v = *(const bf16x8*)&UT[(n*16+fr)*72 + k0*32 + fq*8];
      acc = __builtin_amdgcn_mfma_f32_16x16x32_bf16(a2, b2v, acc, 0, 0, 0);
    }
    #pragma unroll
    for (int r = 0; r < 4; ++r) og[n][r] = acc[r];
  }

  float ss0 = 0.f, ss1 = 0.f, ss2 = 0.f, ss3 = 0.f;
  #pragma unroll
  for (int n = 0; n < 8; ++n) {
    #pragma unroll
    for (int r = 0; r < 4; ++r) {
      int t = w*16 + fq*4 + r, v = n*16 + fr;
      float zf = b2f(Zb[(size_t)(row0+t)*1024 + h*128 + v]);
      float g0 = og[n][r] * siluf(zf);
      og[n][r] = g0;
      float g2 = g0*g0;
      if      (r == 0) ss0 += g2;
      else if (r == 1) ss1 += g2;
      else if (r == 2) ss2 += g2;
      else             ss3 += g2;
    }
  }
  #pragma unroll
  for (int o = 1; o <= 8; o <<= 1) {
    ss0 += __shfl_xor(ss0, o); ss1 += __shfl_xor(ss1, o);
    ss2 += __shfl_xor(ss2, o); ss3 += __shfl_xor(ss3, o);
  }
  float rr[4];
  rr[0] = rsqrtf(ss0*(1.f/128.f) + 1e-6f);
  rr[1] = rsqrtf(ss1*(1.f/128.f) + 1e-6f);
  rr[2] = rsqrtf(ss2*(1.f/128.f) + 1e-6f);
  rr[3] = rsqrtf(ss3*(1.f/128.f) + 1e-6f);
  #pragma unroll
  for (int n = 0; n < 8; ++n) {
    float ow = onw[n*16 + fr];
    #pragma unroll
    for (int r = 0; r < 4; ++r) {
      int t = w*16 + fq*4 + r, v = n*16 + fr;
      ofin[(size_t)(row0+t)*1024 + h*128 + v] = __float2bfloat16(og[n][r] * rr[r] * ow);
    }
  }
}

extern "C" void kernel_launch(void* const* d_in, const int* in_sizes, int n_in,
                              void* d_out, int out_size, void* d_ws, size_t ws_size,
                              hipStream_t stream) {
  const float* hidden     = (const float*)d_in[0];
  const float* Wqkvabz    = (const float*)d_in[1];
  const float* A_log      = (const float*)d_in[2];
  const float* dt_bias    = (const float*)d_in[3];
  const float* conv_state = (const float*)d_in[4];
  const float* w1         = (const float*)d_in[5];
  const float* w2         = (const float*)d_in[6];
  const float* b2         = (const float*)d_in[7];
  const float* init_state = (const float*)d_in[8];
  const float* o_norm_w   = (const float*)d_in[9];
  const float* W_o        = (const float*)d_in[10];
  float* out = (float*)d_out;

  float* ws = (float*)d_ws;
  float* qkvabz = ws;                                  // 6,324,224 f
  float* kern   = qkvabz + (size_t)6324224;            // 8,388,608 f region
  float* zspare = kern   + (size_t)8388608;            // 1,048,576 f -> zb
  float* kn     = zspare + (size_t)1048576;            // 1,048,576
  float* gbuf   = kn     + (size_t)1048576;            // 16,384
  float* bbuf   = gbuf   + (size_t)16384;              // 16,384
  float* vconv  = bbuf   + (size_t)16384;              // 2,097,152
  float* bfpool = vconv  + (size_t)2097152;
  __hip_bfloat16* hidden_bf = (__hip_bfloat16*)bfpool;       // 4,194,304 e
  __hip_bfloat16* w1t   = hidden_bf + (size_t)4194304;       // (spare)
  __hip_bfloat16* w2t   = w1t + (size_t)262144;
  __hip_bfloat16* Wot   = w2t + (size_t)524288;
  __hip_bfloat16* x1sb  = Wot + (size_t)2097152;
  __hip_bfloat16* ofinb = x1sb + (size_t)262144;
  float* Gcbuf  = (float*)(ofinb + (size_t)2097152);         // 16,384 f
  // aliases inside the kern region:
  __hip_bfloat16* Wcat   = (__hip_bfloat16*)kern;            // [3328][2048] bf16 (13.6 MB)
  __hip_bfloat16* kernbf = (__hip_bfloat16*)kern;            // 8,388,608 u16 (w2 out)
  float* Dbuf   = kern + (size_t)2097152;                    // [2M, 3M)
  float* Bvec   = kern + (size_t)3145728;                    // [3M, 5M)
  unsigned short* UvTb  = (unsigned short*)(kern + (size_t)5242880);  // [5M, 6M)
  unsigned short* WnTbb = (unsigned short*)(kern + (size_t)6291456);  // [6M, 6.5M)
  unsigned short* qnb   = (unsigned short*)(kern + (size_t)6815744);  // [6.5M, 7M)
  unsigned short* knb   = (unsigned short*)(kern + (size_t)7340032);  // [7M, 7.5M)
  unsigned short* HcTb  = (unsigned short*)vconv;            // vconv dead after chunkA
  unsigned short* zb    = (unsigned short*)zspare;           // [2048][1024] bf16

  dim3 blk(256);
  prep_k<<<13312, blk, 0, stream>>>(Wqkvabz, w1, w2, W_o, hidden,
                                    Wcat, w2t, Wot, (unsigned short*)hidden_bf);
  // fused qkvabz(+z bf16) + w1 GEMM: M=2048, N=3328, K=2048 -> grid 26x16 = 416
  mgemm_k<3><<<dim3(416),  blk, 0, stream>>>(hidden_bf, Wcat, nullptr, qkvabz, x1sb, zb, 2048, 3328, 2048, 26);
  // w2 GEMM: M=2048, N=4096, K=128 -> grid 32x16 = 512
  mgemm_k<2><<<dim3(512), blk, 0, stream>>>(x1sb, w2t, b2, nullptr, kernbf, nullptr, 2048, 4096, 128, 32);
  // fused actv + conv
  ac_k<<<12288, blk, 0, stream>>>(qkvabz, A_log, dt_bias, kernbf, conv_state,
                                  kn, qnb, knb, gbuf, bbuf, vconv);
  chunkA_k<<<256, blk, 0, stream>>>(kn, knb, vconv, gbuf, bbuf, Gcbuf, Dbuf, Bvec, UvTb, WnTbb);
  chunkB2_k<<<128, blk, 0, stream>>>(Dbuf, Bvec, init_state, HcTb);
  chunkC_k<<<256, blk, 0, stream>>>(qnb, knb, UvTb, WnTbb, Gcbuf, HcTb, zb, o_norm_w, ofinb);
  // out GEMM: M=2048, N=2048, K=1024 -> grid 16x16 = 256
  mgemm_k<0><<<dim3(256),  blk, 0, stream>>>(ofinb, Wot, nullptr, out, nullptr, nullptr, 2048, 2048, 1024, 16);
}

// Round 13
// 178.761 us; speedup vs baseline: 1.0480x; 1.0480x over previous
//
#include <hip/hip_runtime.h>
#include <hip/hip_bf16.h>
#include <math.h>
#include <stdint.h>

#define BATCH 2
#define SEQ 1024
#define HIDDIM 2048
#define NH 8
#define DKD 64
#define DVD 128
#define TKD 512
#define TVD 1024
#define NCOL 3088   // TK+TK+TV+H+H+TV
#define KSZ 4
#define NCHK 16

typedef __attribute__((ext_vector_type(8))) short bf16x8;
typedef __attribute__((ext_vector_type(4))) float f32x4;

__device__ __forceinline__ float sigm(float x){ return 1.f/(1.f+expf(-x)); }
__device__ __forceinline__ float siluf(float x){ return x/(1.f+expf(-x)); }
__device__ __forceinline__ float b2f(unsigned short u){
  union { unsigned int i; float f; } x; x.i = ((unsigned int)u) << 16; return x.f;
}
__device__ __forceinline__ unsigned short f2bu(float f){
  __hip_bfloat16 h = __float2bfloat16(f);
  return *(unsigned short*)&h;
}

__device__ __forceinline__ void glds16(const __hip_bfloat16* g, void* l) {
  __builtin_amdgcn_global_load_lds((const __attribute__((address_space(1))) void*)g,
                                   (__attribute__((address_space(3))) void*)l, 16, 0, 0);
}

// ---------------- fused prep: 4 transposing casts + hidden cast -------------
__global__ __launch_bounds__(256) void prep_k(
    const float* __restrict__ Wqkvabz, const float* __restrict__ w1,
    const float* __restrict__ w2, const float* __restrict__ W_o,
    const float* __restrict__ hidden,
    __hip_bfloat16* __restrict__ Wcat, __hip_bfloat16* __restrict__ w2t,
    __hip_bfloat16* __restrict__ Wot, unsigned short* __restrict__ hidden_bf)
{
  __shared__ float tile[32][33];
  const int blk = blockIdx.x;
  const float* in; __hip_bfloat16* out; int R, C, bx, by;
  if (blk < 6400)      { in=Wqkvabz; out=Wcat; R=2048; C=3088; bx=blk%100; by=blk/100; }
  else if (blk < 6656) { int t=blk-6400; in=w1;  out=Wcat+(size_t)3200*2048; R=2048; C=128;  bx=t%4;   by=t/4; }
  else if (blk < 7168) { int t=blk-6656; in=w2;  out=w2t; R=128;  C=4096; bx=t%128; by=t/128; }
  else if (blk < 9216) { int t=blk-7168; in=W_o; out=Wot; R=1024; C=2048; bx=t%64;  by=t/64; }
  else {
    int i = (blk - 9216)*256 + threadIdx.x;
    float4 v = ((const float4*)hidden)[i];
    ushort4 o; o.x=f2bu(v.x); o.y=f2bu(v.y); o.z=f2bu(v.z); o.w=f2bu(v.w);
    ((ushort4*)hidden_bf)[i] = o;
    return;
  }
  const int tx = threadIdx.x & 31, ty = threadIdx.x >> 5;
  const int c = bx*32 + tx;
  #pragma unroll
  for (int i = 0; i < 4; ++i) {
    int r = by*32 + ty + i*8;
    tile[ty + i*8][tx] = (c < C) ? in[(size_t)r*C + c] : 0.f;
  }
  __syncthreads();
  #pragma unroll
  for (int i = 0; i < 4; ++i) {
    int orow = bx*32 + ty + i*8;
    int ocol = by*32 + tx;
    out[(size_t)orow*R + ocol] = __float2bfloat16(tile[tx][ty + i*8]);
  }
}

// ---------------- bf16 MFMA GEMM, BM=64 x BN=128, depth-3 vmcnt pipeline ----
// (r11 config: 16x16x32 frags, T2 slot swizzle, XCD swizzle)
// EPI: 0 = fp32 out; 2 = +bias -> bf16; 3 = fused qkvabz (all-bf16 + g/beta)
template<int EPI>
__global__ __launch_bounds__(256) void mgemm_k(
    const __hip_bfloat16* __restrict__ A,
    const __hip_bfloat16* __restrict__ Bt,
    const float* __restrict__ bias,
    float* __restrict__ Cf, __hip_bfloat16* __restrict__ Cb,
    unsigned short* __restrict__ Zb, unsigned short* __restrict__ Xs,
    const float* __restrict__ Alog, const float* __restrict__ dtb,
    float* __restrict__ Gp, float* __restrict__ Bp,
    int M, int N, int K, int nbx)
{
  __shared__ __hip_bfloat16 As[3][64*32];
  __shared__ __hip_bfloat16 Bs[3][128*32];
  const int tid = threadIdx.x;
  const int w = tid >> 6, l = tid & 63;
  const int wr = w >> 1, wc = w & 1;
  const int nwg = gridDim.x, q = nwg >> 3;
  const int swz = (blockIdx.x & 7)*q + (blockIdx.x >> 3);
  const int bx = swz % nbx, by = swz / nbx;
  const int row0 = by*64, col0 = bx*128;
  const int fr = l & 15, fq = l >> 4;

  f32x4 acc[2][4];
  #pragma unroll
  for (int m = 0; m < 2; ++m)
    #pragma unroll
    for (int n = 0; n < 4; ++n)
      acc[m][n] = (f32x4){0.f,0.f,0.f,0.f};

  const int ra = w*16 + (l >> 2);
  const int sg = (l & 3) ^ ((ra >> 1) & 3);
  const int ca = sg*8;

  const __hip_bfloat16* pA  = &A[(size_t)(row0 + ra)*K + ca];
  const __hip_bfloat16* pB0 = &Bt[(size_t)(col0 + ra)*K + ca];
  const __hip_bfloat16* pB1 = &Bt[(size_t)(col0 + ra + 64)*K + ca];

  glds16(pA,       (char*)&As[0][0] + w*1024);
  glds16(pB0,      (char*)&Bs[0][0] + w*1024);
  glds16(pB1,      (char*)&Bs[0][0] + 4096 + w*1024);
  if (K > 32) {
    glds16(pA  + 32, (char*)&As[1][0] + w*1024);
    glds16(pB0 + 32, (char*)&Bs[1][0] + w*1024);
    glds16(pB1 + 32, (char*)&Bs[1][0] + 4096 + w*1024);
  }
  if (K > 64) {
    glds16(pA  + 64, (char*)&As[2][0] + w*1024);
    glds16(pB0 + 64, (char*)&Bs[2][0] + w*1024);
    glds16(pB1 + 64, (char*)&Bs[2][0] + 4096 + w*1024);
  }

  int cur = 0;
  for (int k0 = 0; k0 < K; k0 += 32) {
    const int ahead = (K - k0)/32 - 1;
    if (ahead >= 2)      asm volatile("s_waitcnt vmcnt(6)" ::: "memory");
    else if (ahead == 1) asm volatile("s_waitcnt vmcnt(3)" ::: "memory");
    else                 asm volatile("s_waitcnt vmcnt(0)" ::: "memory");
    __builtin_amdgcn_s_barrier();

    bf16x8 af[2], bfv[4];
    #pragma unroll
    for (int m = 0; m < 2; ++m) {
      const int rw = wr*32 + m*16 + fr;
      af[m] = *(const bf16x8*)&As[cur][rw*32 + (fq ^ ((rw>>1)&3))*8];
    }
    #pragma unroll
    for (int n = 0; n < 4; ++n) {
      const int rw = wc*64 + n*16 + fr;
      bfv[n] = *(const bf16x8*)&Bs[cur][rw*32 + (fq ^ ((rw>>1)&3))*8];
    }
    #pragma unroll
    for (int m = 0; m < 2; ++m)
      #pragma unroll
      for (int n = 0; n < 4; ++n)
        acc[m][n] = __builtin_amdgcn_mfma_f32_16x16x32_bf16(af[m], bfv[n], acc[m][n], 0, 0, 0);

    __builtin_amdgcn_s_barrier();
    if (k0 + 96 < K) {
      glds16(pA  + k0 + 96, (char*)&As[cur][0] + w*1024);
      glds16(pB0 + k0 + 96, (char*)&Bs[cur][0] + w*1024);
      glds16(pB1 + k0 + 96, (char*)&Bs[cur][0] + 4096 + w*1024);
    }
    cur = (cur == 2) ? 0 : cur + 1;
  }

  #pragma unroll
  for (int n = 0; n < 4; ++n) {
    const int ccol = col0 + wc*64 + n*16 + fr;
    #pragma unroll
    for (int m = 0; m < 2; ++m) {
      #pragma unroll
      for (int r = 0; r < 4; ++r) {
        const int crow = row0 + wr*32 + m*16 + fq*4 + r;
        float v = acc[m][n][r];
        if (EPI == 0) {
          Cf[(size_t)crow*N + ccol] = v;
        } else if (EPI == 2) {
          Cb[(size_t)crow*N + ccol] = __float2bfloat16(v + bias[ccol]);
        } else { // EPI == 3: all-bf16 split epilogue
          if (ccol < 2048) {            // q|k|v -> qkvb [2048][2048] bf16
            Cb[(size_t)crow*2048 + ccol] = __float2bfloat16(v);
          } else if (ccol < 2056) {     // a -> g
            int h = ccol - 2048;
            float av = v + dtb[h];
            float sp = fmaxf(av, 0.f) + log1pf(expf(-fabsf(av)));
            Gp[(size_t)crow*NH + h] = -expf(Alog[h]) * sp;
          } else if (ccol < 2064) {     // beta
            Bp[(size_t)crow*NH + (ccol - 2056)] = sigm(v);
          } else if (ccol < 3088) {     // z
            Zb[(size_t)crow*1024 + (ccol - 2064)] = f2bu(v);
          } else if (ccol >= 3200) {    // w1 -> silu -> x1s
            Xs[(size_t)crow*128 + (ccol - 3200)] = f2bu(siluf(v));
          }
        }
      }
    }
  }
}

// ---------------- fused actv (silu+l2norm q/k) + dynamic conv ---------------
__global__ __launch_bounds__(256) void ac_k(const unsigned short* __restrict__ qkvb,
    const __hip_bfloat16* __restrict__ kern, const float* __restrict__ conv_state,
    unsigned short* __restrict__ qnb, unsigned short* __restrict__ knb,
    float* __restrict__ vconv)
{
  if (blockIdx.x < 4096) {
    int gid = blockIdx.x*4 + (threadIdx.x >> 6);
    int lane = threadIdx.x & 63;
    int row = gid >> 3; int h = gid & 7;
    const unsigned short* base = qkvb + (size_t)row * 2048;
    float qv = b2f(base[h*64 + lane]);
    float kv = b2f(base[512 + h*64 + lane]);
    float sq = siluf(qv), sk = siluf(kv);
    float ssq = sq*sq, ssk = sk*sk;
    #pragma unroll
    for (int o = 32; o; o >>= 1) { ssq += __shfl_xor(ssq, o); ssk += __shfl_xor(ssk, o); }
    float qn_v = sq * rsqrtf(ssq + 1e-6f) * 0.125f;
    float kn_v = sk * rsqrtf(ssk + 1e-6f);
    size_t idx = (size_t)row*TKD + h*64 + lane;
    qnb[idx] = f2bu(qn_v);
    knb[idx] = f2bu(kn_v);
  } else {
    int idx = (blockIdx.x - 4096)*256 + threadIdx.x;
    int c = idx & (TVD-1);
    int bs = idx >> 10;
    int s = bs & (SEQ-1); int b = bs >> 10;
    ushort4 kf = *(const ushort4*)&kern[(size_t)idx * 4];
    float kj[4] = { b2f(kf.x), b2f(kf.y), b2f(kf.z), b2f(kf.w) };
    float acc = 0.f;
    #pragma unroll
    for (int j = 0; j < 4; ++j) {
      int i = s + j;
      float xv = (i < 3) ? conv_state[((size_t)b*TVD + c)*3 + i]
                         : b2f(qkvb[(size_t)(b*SEQ + (i-3))*2048 + 1024 + c]);
      acc = fmaf(xv, kj[j], acc);
    }
    vconv[idx] = siluf(acc);
  }
}

// ============ chunked gated delta rule =====================================
// Phase A: MFMA A-build + register-column trisolve + fp32 D/b (K from Kb LDS)
__global__ __launch_bounds__(256) void chunkA_k(
   const unsigned short* __restrict__ knb,
   const float* __restrict__ vconv, const float* __restrict__ gb,
   const float* __restrict__ bb, float* __restrict__ Gcbuf,
   float* __restrict__ Dbuf, float* __restrict__ Bvec,
   unsigned short* __restrict__ UvT, unsigned short* __restrict__ WnTb)
{
  const int blk = blockIdx.x;
  const int bh = blk >> 4, c = blk & 15;
  const int b = bh >> 3, h = bh & 7;
  const int tid = threadIdx.x;
  const int w = tid >> 6, l = tid & 63;
  const int fr = l & 15, fq = l >> 4;
  const int row0 = b*SEQ + c*64;

  __shared__ unsigned short Kb[64*72];
  __shared__ float Xv[64][132];
  __shared__ float Xw[64][68];
  __shared__ float AK[64][68];
  __shared__ float Gsh[64], Bsh[64];

  #pragma unroll
  for (int j = 0; j < 2; ++j) {
    int lin = tid + j*256; int t = lin >> 3, dq = (lin & 7)*8;
    *(uint4*)&Kb[t*72+dq] = *(const uint4*)&knb[(size_t)(row0+t)*TKD + h*64 + dq];
  }
  #pragma unroll
  for (int i = 0; i < 8; ++i) {
    int lin = tid + i*256; int t = lin >> 5, v4 = (lin & 31)*4;
    float4 vv = *(const float4*)&vconv[(size_t)(row0+t)*TVD + h*128 + v4];
    Xv[t][v4]=vv.x; Xv[t][v4+1]=vv.y; Xv[t][v4+2]=vv.z; Xv[t][v4+3]=vv.w;
  }
  if (tid < 64) {
    float gv = gb[(size_t)(row0+tid)*NH + h];
    #pragma unroll
    for (int o = 1; o < 64; o <<= 1) {
      float oth = __shfl_up(gv, o);
      if (tid >= o) gv += oth;
    }
    Gsh[tid] = gv;
    Bsh[tid] = bb[(size_t)(row0+tid)*NH + h];
    Gcbuf[(size_t)blk*64 + tid] = gv;
  }
  __syncthreads();

  {
    f32x4 accS[4];
    #pragma unroll
    for (int n = 0; n < 4; ++n) accS[n] = (f32x4){0.f,0.f,0.f,0.f};
    #pragma unroll
    for (int k0 = 0; k0 < 2; ++k0) {
      bf16x8 a = *(const bf16x8*)&Kb[(w*16+fr)*72 + k0*32 + fq*8];
      #pragma unroll
      for (int n = 0; n < 4; ++n) {
        bf16x8 bb2 = *(const bf16x8*)&Kb[(n*16+fr)*72 + k0*32 + fq*8];
        accS[n] = __builtin_amdgcn_mfma_f32_16x16x32_bf16(a, bb2, accS[n], 0, 0, 0);
      }
    }
    #pragma unroll
    for (int n = 0; n < 4; ++n)
      #pragma unroll
      for (int r = 0; r < 4; ++r) {
        int t = w*16 + fq*4 + r, s = n*16 + fr;
        AK[t][s] = (s < t) ? Bsh[t]*expf(Gsh[t]-Gsh[s])*accS[n][r] : 0.f;
      }
  }
  #pragma unroll
  for (int i = 0; i < 4; ++i) {
    int lin = tid + i*256; int t = lin >> 4, d4 = (lin & 15)*4;
    float f = Bsh[t]*expf(Gsh[t]);
    Xw[t][d4+0]=f*b2f(Kb[t*72+d4+0]); Xw[t][d4+1]=f*b2f(Kb[t*72+d4+1]);
    Xw[t][d4+2]=f*b2f(Kb[t*72+d4+2]); Xw[t][d4+3]=f*b2f(Kb[t*72+d4+3]);
  }
  __syncthreads();

  if (tid < 192) {
    float x[64];
    if (tid < 128) {
      #pragma unroll
      for (int t = 0; t < 64; ++t) x[t] = Bsh[t]*Xv[t][tid];
    } else {
      #pragma unroll
      for (int t = 0; t < 64; ++t) x[t] = Xw[t][tid-128];
    }
    #pragma unroll
    for (int t = 1; t < 64; ++t) {
      float a0=0.f, a1=0.f, a2=0.f, a3=0.f;
      #pragma unroll
      for (int s4 = 0; s4 < (t+3)/4; ++s4) {
        float4 av = *(const float4*)&AK[t][s4*4];
        a0 = fmaf(av.x, x[s4*4+0], a0);
        a1 = fmaf(av.y, x[s4*4+1], a1);
        a2 = fmaf(av.z, x[s4*4+2], a2);
        a3 = fmaf(av.w, x[s4*4+3], a3);
      }
      x[t] -= (a0+a1)+(a2+a3);
    }
    if (tid < 128) {
      #pragma unroll
      for (int t = 0; t < 64; ++t) Xv[t][tid] = x[t];
    } else {
      #pragma unroll
      for (int t = 0; t < 64; ++t) Xw[t][tid-128] = x[t];
    }
  }
  __syncthreads();

  const float Gtot = Gsh[63];
  #pragma unroll
  for (int i = 0; i < 4; ++i) {
    int lin = tid + i*256; int t = lin >> 4, d4 = (lin & 15)*4;
    float f = expf(Gtot - Gsh[t]);
    AK[t][d4+0]=f*b2f(Kb[t*72+d4+0]); AK[t][d4+1]=f*b2f(Kb[t*72+d4+1]);
    AK[t][d4+2]=f*b2f(Kb[t*72+d4+2]); AK[t][d4+3]=f*b2f(Kb[t*72+d4+3]);
  }
  __syncthreads();

  {
    const int d1b = (tid >> 4)*4, d2b = (tid & 15)*4;
    float dacc[4][4] = {};
    #pragma unroll 8
    for (int t = 0; t < 64; ++t) {
      float4 kw = *(const float4*)&AK[t][d1b];
      float4 wv = *(const float4*)&Xw[t][d2b];
      float kwa[4] = {kw.x,kw.y,kw.z,kw.w};
      float wva[4] = {wv.x,wv.y,wv.z,wv.w};
      #pragma unroll
      for (int i = 0; i < 4; ++i)
        #pragma unroll
        for (int j = 0; j < 4; ++j)
          dacc[i][j] = fmaf(kwa[i], wva[j], dacc[i][j]);
    }
    const float eG = expf(Gtot);
    #pragma unroll
    for (int i = 0; i < 4; ++i) {
      float vals[4];
      #pragma unroll
      for (int j = 0; j < 4; ++j) {
        float v = -dacc[i][j];
        if (d1b + i == d2b + j) v += eG;
        vals[j] = v;
      }
      *(float4*)&Dbuf[(size_t)blk*4096 + (d1b+i)*64 + d2b] =
        make_float4(vals[0],vals[1],vals[2],vals[3]);
    }
  }
  {
    const int d1b = (tid >> 4)*4, vb = (tid & 15)*8;
    float bacc[4][8] = {};
    #pragma unroll 4
    for (int t = 0; t < 64; ++t) {
      float4 kw = *(const float4*)&AK[t][d1b];
      float4 u0 = *(const float4*)&Xv[t][vb];
      float4 u1 = *(const float4*)&Xv[t][vb+4];
      float kwa[4] = {kw.x,kw.y,kw.z,kw.w};
      float ua[8] = {u0.x,u0.y,u0.z,u0.w,u1.x,u1.y,u1.z,u1.w};
      #pragma unroll
      for (int i = 0; i < 4; ++i)
        #pragma unroll
        for (int j = 0; j < 8; ++j)
          bacc[i][j] = fmaf(kwa[i], ua[j], bacc[i][j]);
    }
    #pragma unroll
    for (int i = 0; i < 4; ++i) {
      *(float4*)&Bvec[(size_t)blk*8192 + (d1b+i)*128 + vb] =
        make_float4(bacc[i][0],bacc[i][1],bacc[i][2],bacc[i][3]);
      *(float4*)&Bvec[(size_t)blk*8192 + (d1b+i)*128 + vb + 4] =
        make_float4(bacc[i][4],bacc[i][5],bacc[i][6],bacc[i][7]);
    }
  }

  {
    #pragma unroll
    for (int i = 0; i < 32; ++i) {
      int v = w*32 + i;
      UvT[(size_t)blk*8192 + v*64 + l] = f2bu(Xv[l][v]);
    }
    #pragma unroll
    for (int i = 0; i < 16; ++i) {
      int d = w*16 + i;
      WnTb[(size_t)blk*4096 + d*64 + l] = f2bu(-Xw[l][d]);
    }
  }
}

// Phase B: h_{c+1} = D_c h_c + b_c ; 128 blocks (bh x 8 vgroups of 16)
__global__ __launch_bounds__(256) void chunkB2_k(const float* __restrict__ Dbuf,
   const float* __restrict__ Bvec, const float* __restrict__ init,
   unsigned short* __restrict__ HcT)
{
  const int blk = blockIdx.x;
  const int bh = blk >> 3, grp = blk & 7;
  const int v0 = grp*16;
  const int tid = threadIdx.x;
  const int v = tid & 15;
  const int d1b = (tid >> 4) * 4;
  __shared__ float DT[64][68];
  __shared__ float bsh[64][17];
  __shared__ float hsh[64][17];

  float hreg[4];
  #pragma unroll
  for (int j = 0; j < 4; ++j) {
    hreg[j] = init[((size_t)bh*64 + d1b + j)*128 + v0 + v];
    hsh[d1b + j][v] = hreg[j];
  }
  float Dreg[16], breg[4];
  {
    const float* Dp = Dbuf + (size_t)(bh*16)*4096;
    const float* bp = Bvec + (size_t)(bh*16)*8192;
    #pragma unroll
    for (int i = 0; i < 16; ++i) Dreg[i] = Dp[tid + i*256];
    #pragma unroll
    for (int i = 0; i < 4; ++i)  breg[i] = bp[(size_t)((tid>>4) + i*16)*128 + v0 + v];
  }
  #pragma unroll
  for (int i = 0; i < 16; ++i) {
    int cell = tid + i*256; DT[cell & 63][cell >> 6] = Dreg[i];
  }
  #pragma unroll
  for (int i = 0; i < 4; ++i) bsh[(tid>>4) + i*16][v] = breg[i];
  __syncthreads();

  for (int c = 0; c < 16; ++c) {
    if (c < 15) {
      const float* Dn = Dbuf + (size_t)(bh*16 + c + 1)*4096;
      const float* bn = Bvec + (size_t)(bh*16 + c + 1)*8192;
      #pragma unroll
      for (int i = 0; i < 16; ++i) Dreg[i] = Dn[tid + i*256];
      #pragma unroll
      for (int i = 0; i < 4; ++i)  breg[i] = bn[(size_t)((tid>>4) + i*16)*128 + v0 + v];
    }
    #pragma unroll
    for (int j = 0; j < 4; ++j)
      HcT[(size_t)(bh*16 + c)*8192 + (size_t)(v0+v)*64 + d1b + j] = f2bu(hreg[j]);
    float nh[4];
    #pragma unroll
    for (int j = 0; j < 4; ++j) nh[j] = bsh[d1b + j][v];
    #pragma unroll 8
    for (int d2 = 0; d2 < 64; ++d2) {
      float hv = hsh[d2][v];
      float4 dv = *(const float4*)&DT[d2][d1b];
      nh[0] = fmaf(dv.x, hv, nh[0]);
      nh[1] = fmaf(dv.y, hv, nh[1]);
      nh[2] = fmaf(dv.z, hv, nh[2]);
      nh[3] = fmaf(dv.w, hv, nh[3]);
    }
    __syncthreads();
    #pragma unroll
    for (int j = 0; j < 4; ++j) { hreg[j] = nh[j]; hsh[d1b + j][v] = nh[j]; }
    if (c < 15) {
      #pragma unroll
      for (int i = 0; i < 16; ++i) {
        int cell = tid + i*256; DT[cell & 63][cell >> 6] = Dreg[i];
      }
      #pragma unroll
      for (int i = 0; i < 4; ++i) bsh[(tid>>4) + i*16][v] = breg[i];
    }
    __syncthreads();
  }
}

// Phase C (MFMA): S = decayed-masked QK^T; Qt = E.Q - S Wt; o = Qt h + S U;
// fused gated RMSNorm -> ofin bf16
__global__ __launch_bounds__(256) void chunkC_k(
   const unsigned short* __restrict__ qnb, const unsigned short* __restrict__ knb,
   const unsigned short* __restrict__ UvT, const unsigned short* __restrict__ WnTb,
   const float* __restrict__ Gcbuf, const unsigned short* __restrict__ HcT,
   const unsigned short* __restrict__ Zb, const float* __restrict__ onw,
   __hip_bfloat16* __restrict__ ofin)
{
  const int blk = blockIdx.x; const int bh = blk >> 4, c = blk & 15;
  const int b = bh >> 3, h = bh & 7;
  const int row0 = b*SEQ + c*64;
  const int tid = threadIdx.x;
  const int w = tid >> 6, l = tid & 63;
  const int fr = l & 15, fq = l >> 4;

  __shared__ unsigned short Qs[64*72];
  __shared__ unsigned short Ks[64*72];
  __shared__ unsigned short Ws[64*72];
  __shared__ unsigned short hT[128*72];
  __shared__ unsigned short UT[128*72];
  __shared__ unsigned short Ss[64*72];
  __shared__ float Gsh[64], Esh[64];

  #pragma unroll
  for (int j = 0; j < 2; ++j) {
    int lin = tid + j*256; int t = lin >> 3, dq = (lin & 7)*8;
    *(uint4*)&Qs[t*72+dq] = *(const uint4*)&qnb[(size_t)(row0+t)*TKD + h*64 + dq];
    *(uint4*)&Ks[t*72+dq] = *(const uint4*)&knb[(size_t)(row0+t)*TKD + h*64 + dq];
    *(uint4*)&Ws[t*72+dq] = *(const uint4*)&WnTb[(size_t)blk*4096 + t*64 + dq];
  }
  #pragma unroll
  for (int j = 0; j < 4; ++j) {
    int lin = tid + j*256; int v = lin >> 3, dq = (lin & 7)*8;
    *(uint4*)&hT[v*72+dq] = *(const uint4*)&HcT[(size_t)blk*8192 + (size_t)v*64 + dq];
    *(uint4*)&UT[v*72+dq] = *(const uint4*)&UvT[(size_t)blk*8192 + (size_t)v*64 + dq];
  }
  if (tid < 64) { float g = Gcbuf[(size_t)blk*64 + tid]; Gsh[tid] = g; Esh[tid] = expf(g); }
  __syncthreads();

  f32x4 accS[4];
  #pragma unroll
  for (int n = 0; n < 4; ++n) accS[n] = (f32x4){0.f,0.f,0.f,0.f};
  #pragma unroll
  for (int k0 = 0; k0 < 2; ++k0) {
    bf16x8 a = *(const bf16x8*)&Qs[(w*16+fr)*72 + k0*32 + fq*8];
    #pragma unroll
    for (int n = 0; n < 4; ++n) {
      bf16x8 bb = *(const bf16x8*)&Ks[(n*16+fr)*72 + k0*32 + fq*8];
      accS[n] = __builtin_amdgcn_mfma_f32_16x16x32_bf16(a, bb, accS[n], 0, 0, 0);
    }
  }
  #pragma unroll
  for (int n = 0; n < 4; ++n)
    #pragma unroll
    for (int r = 0; r < 4; ++r) {
      int t = w*16 + fq*4 + r, s = n*16 + fr;
      float val = (s <= t) ? expf(Gsh[t]-Gsh[s]) * accS[n][r] : 0.f;
      Ss[t*72 + s] = f2bu(val);
    }

  f32x4 accQ[4];
  #pragma unroll
  for (int n = 0; n < 4; ++n) {
    #pragma unroll
    for (int r = 0; r < 4; ++r) {
      int t = w*16 + fq*4 + r, d = n*16 + fr;
      accQ[n][r] = Esh[t] * b2f(Qs[t*72 + d]);
    }
    #pragma unroll
    for (int k0 = 0; k0 < 2; ++k0) {
      bf16x8 a = *(const bf16x8*)&Ss[(w*16+fr)*72 + k0*32 + fq*8];
      bf16x8 bb = *(const bf16x8*)&Ws[(n*16+fr)*72 + k0*32 + fq*8];
      accQ[n] = __builtin_amdgcn_mfma_f32_16x16x32_bf16(a, bb, accQ[n], 0, 0, 0);
    }
  }
  __syncthreads();

  #pragma unroll
  for (int n = 0; n < 4; ++n)
    #pragma unroll
    for (int r = 0; r < 4; ++r) {
      int t = w*16 + fq*4 + r, d = n*16 + fr;
      Ks[t*72 + d] = f2bu(accQ[n][r]);
    }

  float og[8][4];
  #pragma unroll
  for (int n = 0; n < 8; ++n) {
    f32x4 acc = (f32x4){0.f,0.f,0.f,0.f};
    #pragma unroll
    for (int k0 = 0; k0 < 2; ++k0) {
      bf16x8 a1 = *(const bf16x8*)&Ks[(w*16+fr)*72 + k0*32 + fq*8];
      bf16x8 b1 = *(const bf16x8*)&hT[(n*16+fr)*72 + k0*32 + fq*8];
      acc = __builtin_amdgcn_mfma_f32_16x16x32_bf16(a1, b1, acc, 0, 0, 0);
      bf16x8 a2 = *(const bf16x8*)&Ss[(w*16+fr)*72 + k0*32 + fq*8];
      bf16x8 b2v = *(const bf16x8*)&UT[(n*16+fr)*72 + k0*32 + fq*8];
      acc = __builtin_amdgcn_mfma_f32_16x16x32_bf16(a2, b2v, acc, 0, 0, 0);
    }
    #pragma unroll
    for (int r = 0; r < 4; ++r) og[n][r] = acc[r];
  }

  float ss0 = 0.f, ss1 = 0.f, ss2 = 0.f, ss3 = 0.f;
  #pragma unroll
  for (int n = 0; n < 8; ++n) {
    #pragma unroll
    for (int r = 0; r < 4; ++r) {
      int t = w*16 + fq*4 + r, v = n*16 + fr;
      float zf = b2f(Zb[(size_t)(row0+t)*1024 + h*128 + v]);
      float g0 = og[n][r] * siluf(zf);
      og[n][r] = g0;
      float g2 = g0*g0;
      if      (r == 0) ss0 += g2;
      else if (r == 1) ss1 += g2;
      else if (r == 2) ss2 += g2;
      else             ss3 += g2;
    }
  }
  #pragma unroll
  for (int o = 1; o <= 8; o <<= 1) {
    ss0 += __shfl_xor(ss0, o); ss1 += __shfl_xor(ss1, o);
    ss2 += __shfl_xor(ss2, o); ss3 += __shfl_xor(ss3, o);
  }
  float rr[4];
  rr[0] = rsqrtf(ss0*(1.f/128.f) + 1e-6f);
  rr[1] = rsqrtf(ss1*(1.f/128.f) + 1e-6f);
  rr[2] = rsqrtf(ss2*(1.f/128.f) + 1e-6f);
  rr[3] = rsqrtf(ss3*(1.f/128.f) + 1e-6f);
  #pragma unroll
  for (int n = 0; n < 8; ++n) {
    float ow = onw[n*16 + fr];
    #pragma unroll
    for (int r = 0; r < 4; ++r) {
      int t = w*16 + fq*4 + r, v = n*16 + fr;
      ofin[(size_t)(row0+t)*1024 + h*128 + v] = __float2bfloat16(og[n][r] * rr[r] * ow);
    }
  }
}

extern "C" void kernel_launch(void* const* d_in, const int* in_sizes, int n_in,
                              void* d_out, int out_size, void* d_ws, size_t ws_size,
                              hipStream_t stream) {
  const float* hidden     = (const float*)d_in[0];
  const float* Wqkvabz    = (const float*)d_in[1];
  const float* A_log      = (const float*)d_in[2];
  const float* dt_bias    = (const float*)d_in[3];
  const float* conv_state = (const float*)d_in[4];
  const float* w1         = (const float*)d_in[5];
  const float* w2         = (const float*)d_in[6];
  const float* b2         = (const float*)d_in[7];
  const float* init_state = (const float*)d_in[8];
  const float* o_norm_w   = (const float*)d_in[9];
  const float* W_o        = (const float*)d_in[10];
  float* out = (float*)d_out;

  float* ws = (float*)d_ws;
  float* qregion = ws;                                 // 6,324,224 f (qkvb lives here)
  float* kern   = qregion + (size_t)6324224;           // 8,388,608 f region
  float* zspare = kern   + (size_t)8388608;            // 1,048,576 f -> zb
  float* knsp   = zspare + (size_t)1048576;            // 1,048,576 (spare)
  float* gbuf   = knsp   + (size_t)1048576;            // 16,384
  float* bbuf   = gbuf   + (size_t)16384;              // 16,384
  float* vconv  = bbuf   + (size_t)16384;              // 2,097,152
  float* bfpool = vconv  + (size_t)2097152;
  __hip_bfloat16* hidden_bf = (__hip_bfloat16*)bfpool;       // 4,194,304 e
  __hip_bfloat16* w1t   = hidden_bf + (size_t)4194304;       // (spare)
  __hip_bfloat16* w2t   = w1t + (size_t)262144;
  __hip_bfloat16* Wot   = w2t + (size_t)524288;
  __hip_bfloat16* x1sb  = Wot + (size_t)2097152;
  __hip_bfloat16* ofinb = x1sb + (size_t)262144;
  float* Gcbuf  = (float*)(ofinb + (size_t)2097152);         // 16,384 f
  // aliases:
  unsigned short* qkvb   = (unsigned short*)qregion;         // [2048][2048] bf16
  __hip_bfloat16* Wcat   = (__hip_bfloat16*)kern;            // [3328][2048] bf16
  __hip_bfloat16* kernbf = (__hip_bfloat16*)kern;            // 8,388,608 u16 (w2 out)
  float* Dbuf   = kern + (size_t)2097152;                    // [2M, 3M)
  float* Bvec   = kern + (size_t)3145728;                    // [3M, 5M)
  unsigned short* UvTb  = (unsigned short*)(kern + (size_t)5242880);
  unsigned short* WnTbb = (unsigned short*)(kern + (size_t)6291456);
  unsigned short* qnb   = (unsigned short*)(kern + (size_t)6815744);
  unsigned short* knb   = (unsigned short*)(kern + (size_t)7340032);
  unsigned short* HcTb  = (unsigned short*)vconv;            // vconv dead after chunkA
  unsigned short* zb    = (unsigned short*)zspare;           // [2048][1024] bf16

  dim3 blk(256);
  prep_k<<<13312, blk, 0, stream>>>(Wqkvabz, w1, w2, W_o, hidden,
                                    Wcat, w2t, Wot, (unsigned short*)hidden_bf);
  // fused qkvabz(all-bf16) + w1 GEMM: M=2048, N=3328, K=2048 -> 26x32 = 832
  mgemm_k<3><<<dim3(832),  blk, 0, stream>>>(hidden_bf, Wcat, nullptr,
      nullptr, (__hip_bfloat16*)qkvb, zb, (unsigned short*)x1sb,
      A_log, dt_bias, gbuf, bbuf, 2048, 3328, 2048, 26);
  // w2 GEMM: M=2048, N=4096, K=128 -> 32x32 = 1024
  mgemm_k<2><<<dim3(1024), blk, 0, stream>>>(x1sb, w2t, b2,
      nullptr, kernbf, nullptr, nullptr, nullptr, nullptr, nullptr, nullptr,
      2048, 4096, 128, 32);
  // fused actv + conv (bf16 inputs)
  ac_k<<<12288, blk, 0, stream>>>(qkvb, kernbf, conv_state, qnb, knb, vconv);
  chunkA_k<<<256, blk, 0, stream>>>(knb, vconv, gbuf, bbuf, Gcbuf, Dbuf, Bvec, UvTb, WnTbb);
  chunkB2_k<<<128, blk, 0, stream>>>(Dbuf, Bvec, init_state, HcTb);
  chunkC_k<<<256, blk, 0, stream>>>(qnb, knb, UvTb, WnTbb, Gcbuf, HcTb, zb, o_norm_w, ofinb);
  // out GEMM: M=2048, N=2048, K=1024 -> 16x32 = 512
  mgemm_k<0><<<dim3(512),  blk, 0, stream>>>(ofinb, Wot, nullptr,
      out, nullptr, nullptr, nullptr, nullptr, nullptr, nullptr, nullptr,
      2048, 2048, 1024, 16);
}

// Round 14
// 178.403 us; speedup vs baseline: 1.0501x; 1.0020x over previous
//
#include <hip/hip_runtime.h>
#include <hip/hip_bf16.h>
#include <math.h>
#include <stdint.h>

#define BATCH 2
#define SEQ 1024
#define HIDDIM 2048
#define NH 8
#define DKD 64
#define DVD 128
#define TKD 512
#define TVD 1024
#define NCOL 3088   // TK+TK+TV+H+H+TV
#define KSZ 4
#define NCHK 16

typedef __attribute__((ext_vector_type(8))) short bf16x8;
typedef __attribute__((ext_vector_type(4))) float f32x4;

__device__ __forceinline__ float sigm(float x){ return 1.f/(1.f+expf(-x)); }
__device__ __forceinline__ float siluf(float x){ return x/(1.f+expf(-x)); }
__device__ __forceinline__ float b2f(unsigned short u){
  union { unsigned int i; float f; } x; x.i = ((unsigned int)u) << 16; return x.f;
}
__device__ __forceinline__ unsigned short f2bu(float f){
  __hip_bfloat16 h = __float2bfloat16(f);
  return *(unsigned short*)&h;
}

__device__ __forceinline__ void glds16(const __hip_bfloat16* g, void* l) {
  __builtin_amdgcn_global_load_lds((const __attribute__((address_space(1))) void*)g,
                                   (__attribute__((address_space(3))) void*)l, 16, 0, 0);
}

// ---------------- fused prep: 4 transposing casts + hidden cast -------------
__global__ __launch_bounds__(256) void prep_k(
    const float* __restrict__ Wqkvabz, const float* __restrict__ w1,
    const float* __restrict__ w2, const float* __restrict__ W_o,
    const float* __restrict__ hidden,
    __hip_bfloat16* __restrict__ Wcat, __hip_bfloat16* __restrict__ w2t,
    __hip_bfloat16* __restrict__ Wot, unsigned short* __restrict__ hidden_bf)
{
  __shared__ float tile[32][33];
  const int blk = blockIdx.x;
  const float* in; __hip_bfloat16* out; int R, C, bx, by;
  if (blk < 6400)      { in=Wqkvabz; out=Wcat; R=2048; C=3088; bx=blk%100; by=blk/100; }
  else if (blk < 6656) { int t=blk-6400; in=w1;  out=Wcat+(size_t)3200*2048; R=2048; C=128;  bx=t%4;   by=t/4; }
  else if (blk < 7168) { int t=blk-6656; in=w2;  out=w2t; R=128;  C=4096; bx=t%128; by=t/128; }
  else if (blk < 9216) { int t=blk-7168; in=W_o; out=Wot; R=1024; C=2048; bx=t%64;  by=t/64; }
  else {
    int i = (blk - 9216)*256 + threadIdx.x;
    float4 v = ((const float4*)hidden)[i];
    ushort4 o; o.x=f2bu(v.x); o.y=f2bu(v.y); o.z=f2bu(v.z); o.w=f2bu(v.w);
    ((ushort4*)hidden_bf)[i] = o;
    return;
  }
  const int tx = threadIdx.x & 31, ty = threadIdx.x >> 5;
  const int c = bx*32 + tx;
  #pragma unroll
  for (int i = 0; i < 4; ++i) {
    int r = by*32 + ty + i*8;
    tile[ty + i*8][tx] = (c < C) ? in[(size_t)r*C + c] : 0.f;
  }
  __syncthreads();
  #pragma unroll
  for (int i = 0; i < 4; ++i) {
    int orow = bx*32 + ty + i*8;
    int ocol = by*32 + tx;
    out[(size_t)orow*R + ocol] = __float2bfloat16(tile[tx][ty + i*8]);
  }
}

// ---------------- bf16 MFMA GEMM, BM=64 x BN=128, depth-3 vmcnt pipeline ----
// (16x16x32 frags, T2 slot swizzle, XCD swizzle)
// Block order: within an XCD chunk the FAST axis is by (A tiles) so the
// B-panel tile (0.5 MB) stays L2-resident across 32 consecutive blocks.
// EPI: 0 = fp32 out; 2 = +bias -> bf16; 3 = fused qkvabz (all-bf16 + g/beta)
template<int EPI>
__global__ __launch_bounds__(256) void mgemm_k(
    const __hip_bfloat16* __restrict__ A,
    const __hip_bfloat16* __restrict__ Bt,
    const float* __restrict__ bias,
    float* __restrict__ Cf, __hip_bfloat16* __restrict__ Cb,
    unsigned short* __restrict__ Zb, unsigned short* __restrict__ Xs,
    const float* __restrict__ Alog, const float* __restrict__ dtb,
    float* __restrict__ Gp, float* __restrict__ Bp,
    int M, int N, int K, int nby)
{
  __shared__ __hip_bfloat16 As[3][64*32];
  __shared__ __hip_bfloat16 Bs[3][128*32];
  const int tid = threadIdx.x;
  const int w = tid >> 6, l = tid & 63;
  const int wr = w >> 1, wc = w & 1;
  const int nwg = gridDim.x, q = nwg >> 3;
  const int swz = (blockIdx.x & 7)*q + (blockIdx.x >> 3);
  const int by = swz % nby, bx = swz / nby;   // fast axis = by -> B-tile reuse
  const int row0 = by*64, col0 = bx*128;
  const int fr = l & 15, fq = l >> 4;

  f32x4 acc[2][4];
  #pragma unroll
  for (int m = 0; m < 2; ++m)
    #pragma unroll
    for (int n = 0; n < 4; ++n)
      acc[m][n] = (f32x4){0.f,0.f,0.f,0.f};

  const int ra = w*16 + (l >> 2);
  const int sg = (l & 3) ^ ((ra >> 1) & 3);
  const int ca = sg*8;

  const __hip_bfloat16* pA  = &A[(size_t)(row0 + ra)*K + ca];
  const __hip_bfloat16* pB0 = &Bt[(size_t)(col0 + ra)*K + ca];
  const __hip_bfloat16* pB1 = &Bt[(size_t)(col0 + ra + 64)*K + ca];

  glds16(pA,       (char*)&As[0][0] + w*1024);
  glds16(pB0,      (char*)&Bs[0][0] + w*1024);
  glds16(pB1,      (char*)&Bs[0][0] + 4096 + w*1024);
  if (K > 32) {
    glds16(pA  + 32, (char*)&As[1][0] + w*1024);
    glds16(pB0 + 32, (char*)&Bs[1][0] + w*1024);
    glds16(pB1 + 32, (char*)&Bs[1][0] + 4096 + w*1024);
  }
  if (K > 64) {
    glds16(pA  + 64, (char*)&As[2][0] + w*1024);
    glds16(pB0 + 64, (char*)&Bs[2][0] + w*1024);
    glds16(pB1 + 64, (char*)&Bs[2][0] + 4096 + w*1024);
  }

  int cur = 0;
  for (int k0 = 0; k0 < K; k0 += 32) {
    const int ahead = (K - k0)/32 - 1;
    if (ahead >= 2)      asm volatile("s_waitcnt vmcnt(6)" ::: "memory");
    else if (ahead == 1) asm volatile("s_waitcnt vmcnt(3)" ::: "memory");
    else                 asm volatile("s_waitcnt vmcnt(0)" ::: "memory");
    __builtin_amdgcn_s_barrier();

    bf16x8 af[2], bfv[4];
    #pragma unroll
    for (int m = 0; m < 2; ++m) {
      const int rw = wr*32 + m*16 + fr;
      af[m] = *(const bf16x8*)&As[cur][rw*32 + (fq ^ ((rw>>1)&3))*8];
    }
    #pragma unroll
    for (int n = 0; n < 4; ++n) {
      const int rw = wc*64 + n*16 + fr;
      bfv[n] = *(const bf16x8*)&Bs[cur][rw*32 + (fq ^ ((rw>>1)&3))*8];
    }
    #pragma unroll
    for (int m = 0; m < 2; ++m)
      #pragma unroll
      for (int n = 0; n < 4; ++n)
        acc[m][n] = __builtin_amdgcn_mfma_f32_16x16x32_bf16(af[m], bfv[n], acc[m][n], 0, 0, 0);

    __builtin_amdgcn_s_barrier();
    if (k0 + 96 < K) {
      glds16(pA  + k0 + 96, (char*)&As[cur][0] + w*1024);
      glds16(pB0 + k0 + 96, (char*)&Bs[cur][0] + w*1024);
      glds16(pB1 + k0 + 96, (char*)&Bs[cur][0] + 4096 + w*1024);
    }
    cur = (cur == 2) ? 0 : cur + 1;
  }

  #pragma unroll
  for (int n = 0; n < 4; ++n) {
    const int ccol = col0 + wc*64 + n*16 + fr;
    #pragma unroll
    for (int m = 0; m < 2; ++m) {
      #pragma unroll
      for (int r = 0; r < 4; ++r) {
        const int crow = row0 + wr*32 + m*16 + fq*4 + r;
        float v = acc[m][n][r];
        if (EPI == 0) {
          Cf[(size_t)crow*N + ccol] = v;
        } else if (EPI == 2) {
          Cb[(size_t)crow*N + ccol] = __float2bfloat16(v + bias[ccol]);
        } else { // EPI == 3: all-bf16 split epilogue
          if (ccol < 2048) {            // q|k|v -> qkvb [2048][2048] bf16
            Cb[(size_t)crow*2048 + ccol] = __float2bfloat16(v);
          } else if (ccol < 2056) {     // a -> g
            int h = ccol - 2048;
            float av = v + dtb[h];
            float sp = fmaxf(av, 0.f) + log1pf(expf(-fabsf(av)));
            Gp[(size_t)crow*NH + h] = -expf(Alog[h]) * sp;
          } else if (ccol < 2064) {     // beta
            Bp[(size_t)crow*NH + (ccol - 2056)] = sigm(v);
          } else if (ccol < 3088) {     // z
            Zb[(size_t)crow*1024 + (ccol - 2064)] = f2bu(v);
          } else if (ccol >= 3200) {    // w1 -> silu -> x1s
            Xs[(size_t)crow*128 + (ccol - 3200)] = f2bu(siluf(v));
          }
        }
      }
    }
  }
}

// ---------------- fused actv (silu+l2norm q/k) + dynamic conv ---------------
__global__ __launch_bounds__(256) void ac_k(const unsigned short* __restrict__ qkvb,
    const __hip_bfloat16* __restrict__ kern, const float* __restrict__ conv_state,
    unsigned short* __restrict__ qnb, unsigned short* __restrict__ knb,
    float* __restrict__ vconv)
{
  if (blockIdx.x < 4096) {
    int gid = blockIdx.x*4 + (threadIdx.x >> 6);
    int lane = threadIdx.x & 63;
    int row = gid >> 3; int h = gid & 7;
    const unsigned short* base = qkvb + (size_t)row * 2048;
    float qv = b2f(base[h*64 + lane]);
    float kv = b2f(base[512 + h*64 + lane]);
    float sq = siluf(qv), sk = siluf(kv);
    float ssq = sq*sq, ssk = sk*sk;
    #pragma unroll
    for (int o = 32; o; o >>= 1) { ssq += __shfl_xor(ssq, o); ssk += __shfl_xor(ssk, o); }
    float qn_v = sq * rsqrtf(ssq + 1e-6f) * 0.125f;
    float kn_v = sk * rsqrtf(ssk + 1e-6f);
    size_t idx = (size_t)row*TKD + h*64 + lane;
    qnb[idx] = f2bu(qn_v);
    knb[idx] = f2bu(kn_v);
  } else {
    int idx = (blockIdx.x - 4096)*256 + threadIdx.x;
    int c = idx & (TVD-1);
    int bs = idx >> 10;
    int s = bs & (SEQ-1); int b = bs >> 10;
    ushort4 kf = *(const ushort4*)&kern[(size_t)idx * 4];
    float kj[4] = { b2f(kf.x), b2f(kf.y), b2f(kf.z), b2f(kf.w) };
    float acc = 0.f;
    #pragma unroll
    for (int j = 0; j < 4; ++j) {
      int i = s + j;
      float xv = (i < 3) ? conv_state[((size_t)b*TVD + c)*3 + i]
                         : b2f(qkvb[(size_t)(b*SEQ + (i-3))*2048 + 1024 + c]);
      acc = fmaf(xv, kj[j], acc);
    }
    vconv[idx] = siluf(acc);
  }
}

// ============ chunked gated delta rule =====================================
// Phase A: MFMA A-build + register-column trisolve + fp32 D/b (K from Kb LDS)
__global__ __launch_bounds__(256) void chunkA_k(
   const unsigned short* __restrict__ knb,
   const float* __restrict__ vconv, const float* __restrict__ gb,
   const float* __restrict__ bb, float* __restrict__ Gcbuf,
   float* __restrict__ Dbuf, float* __restrict__ Bvec,
   unsigned short* __restrict__ UvT, unsigned short* __restrict__ WnTb)
{
  const int blk = blockIdx.x;
  const int bh = blk >> 4, c = blk & 15;
  const int b = bh >> 3, h = bh & 7;
  const int tid = threadIdx.x;
  const int w = tid >> 6, l = tid & 63;
  const int fr = l & 15, fq = l >> 4;
  const int row0 = b*SEQ + c*64;

  __shared__ unsigned short Kb[64*72];
  __shared__ float Xv[64][132];
  __shared__ float Xw[64][68];
  __shared__ float AK[64][68];
  __shared__ float Gsh[64], Bsh[64];

  #pragma unroll
  for (int j = 0; j < 2; ++j) {
    int lin = tid + j*256; int t = lin >> 3, dq = (lin & 7)*8;
    *(uint4*)&Kb[t*72+dq] = *(const uint4*)&knb[(size_t)(row0+t)*TKD + h*64 + dq];
  }
  #pragma unroll
  for (int i = 0; i < 8; ++i) {
    int lin = tid + i*256; int t = lin >> 5, v4 = (lin & 31)*4;
    float4 vv = *(const float4*)&vconv[(size_t)(row0+t)*TVD + h*128 + v4];
    Xv[t][v4]=vv.x; Xv[t][v4+1]=vv.y; Xv[t][v4+2]=vv.z; Xv[t][v4+3]=vv.w;
  }
  if (tid < 64) {
    float gv = gb[(size_t)(row0+tid)*NH + h];
    #pragma unroll
    for (int o = 1; o < 64; o <<= 1) {
      float oth = __shfl_up(gv, o);
      if (tid >= o) gv += oth;
    }
    Gsh[tid] = gv;
    Bsh[tid] = bb[(size_t)(row0+tid)*NH + h];
    Gcbuf[(size_t)blk*64 + tid] = gv;
  }
  __syncthreads();

  {
    f32x4 accS[4];
    #pragma unroll
    for (int n = 0; n < 4; ++n) accS[n] = (f32x4){0.f,0.f,0.f,0.f};
    #pragma unroll
    for (int k0 = 0; k0 < 2; ++k0) {
      bf16x8 a = *(const bf16x8*)&Kb[(w*16+fr)*72 + k0*32 + fq*8];
      #pragma unroll
      for (int n = 0; n < 4; ++n) {
        bf16x8 bb2 = *(const bf16x8*)&Kb[(n*16+fr)*72 + k0*32 + fq*8];
        accS[n] = __builtin_amdgcn_mfma_f32_16x16x32_bf16(a, bb2, accS[n], 0, 0, 0);
      }
    }
    #pragma unroll
    for (int n = 0; n < 4; ++n)
      #pragma unroll
      for (int r = 0; r < 4; ++r) {
        int t = w*16 + fq*4 + r, s = n*16 + fr;
        AK[t][s] = (s < t) ? Bsh[t]*expf(Gsh[t]-Gsh[s])*accS[n][r] : 0.f;
      }
  }
  #pragma unroll
  for (int i = 0; i < 4; ++i) {
    int lin = tid + i*256; int t = lin >> 4, d4 = (lin & 15)*4;
    float f = Bsh[t]*expf(Gsh[t]);
    Xw[t][d4+0]=f*b2f(Kb[t*72+d4+0]); Xw[t][d4+1]=f*b2f(Kb[t*72+d4+1]);
    Xw[t][d4+2]=f*b2f(Kb[t*72+d4+2]); Xw[t][d4+3]=f*b2f(Kb[t*72+d4+3]);
  }
  __syncthreads();

  if (tid < 192) {
    float x[64];
    if (tid < 128) {
      #pragma unroll
      for (int t = 0; t < 64; ++t) x[t] = Bsh[t]*Xv[t][tid];
    } else {
      #pragma unroll
      for (int t = 0; t < 64; ++t) x[t] = Xw[t][tid-128];
    }
    #pragma unroll
    for (int t = 1; t < 64; ++t) {
      float a0=0.f, a1=0.f, a2=0.f, a3=0.f;
      #pragma unroll
      for (int s4 = 0; s4 < (t+3)/4; ++s4) {
        float4 av = *(const float4*)&AK[t][s4*4];
        a0 = fmaf(av.x, x[s4*4+0], a0);
        a1 = fmaf(av.y, x[s4*4+1], a1);
        a2 = fmaf(av.z, x[s4*4+2], a2);
        a3 = fmaf(av.w, x[s4*4+3], a3);
      }
      x[t] -= (a0+a1)+(a2+a3);
    }
    if (tid < 128) {
      #pragma unroll
      for (int t = 0; t < 64; ++t) Xv[t][tid] = x[t];
    } else {
      #pragma unroll
      for (int t = 0; t < 64; ++t) Xw[t][tid-128] = x[t];
    }
  }
  __syncthreads();

  const float Gtot = Gsh[63];
  #pragma unroll
  for (int i = 0; i < 4; ++i) {
    int lin = tid + i*256; int t = lin >> 4, d4 = (lin & 15)*4;
    float f = expf(Gtot - Gsh[t]);
    AK[t][d4+0]=f*b2f(Kb[t*72+d4+0]); AK[t][d4+1]=f*b2f(Kb[t*72+d4+1]);
    AK[t][d4+2]=f*b2f(Kb[t*72+d4+2]); AK[t][d4+3]=f*b2f(Kb[t*72+d4+3]);
  }
  __syncthreads();

  {
    const int d1b = (tid >> 4)*4, d2b = (tid & 15)*4;
    float dacc[4][4] = {};
    #pragma unroll 8
    for (int t = 0; t < 64; ++t) {
      float4 kw = *(const float4*)&AK[t][d1b];
      float4 wv = *(const float4*)&Xw[t][d2b];
      float kwa[4] = {kw.x,kw.y,kw.z,kw.w};
      float wva[4] = {wv.x,wv.y,wv.z,wv.w};
      #pragma unroll
      for (int i = 0; i < 4; ++i)
        #pragma unroll
        for (int j = 0; j < 4; ++j)
          dacc[i][j] = fmaf(kwa[i], wva[j], dacc[i][j]);
    }
    const float eG = expf(Gtot);
    #pragma unroll
    for (int i = 0; i < 4; ++i) {
      float vals[4];
      #pragma unroll
      for (int j = 0; j < 4; ++j) {
        float v = -dacc[i][j];
        if (d1b + i == d2b + j) v += eG;
        vals[j] = v;
      }
      *(float4*)&Dbuf[(size_t)blk*4096 + (d1b+i)*64 + d2b] =
        make_float4(vals[0],vals[1],vals[2],vals[3]);
    }
  }
  {
    const int d1b = (tid >> 4)*4, vb = (tid & 15)*8;
    float bacc[4][8] = {};
    #pragma unroll 4
    for (int t = 0; t < 64; ++t) {
      float4 kw = *(const float4*)&AK[t][d1b];
      float4 u0 = *(const float4*)&Xv[t][vb];
      float4 u1 = *(const float4*)&Xv[t][vb+4];
      float kwa[4] = {kw.x,kw.y,kw.z,kw.w};
      float ua[8] = {u0.x,u0.y,u0.z,u0.w,u1.x,u1.y,u1.z,u1.w};
      #pragma unroll
      for (int i = 0; i < 4; ++i)
        #pragma unroll
        for (int j = 0; j < 8; ++j)
          bacc[i][j] = fmaf(kwa[i], ua[j], bacc[i][j]);
    }
    #pragma unroll
    for (int i = 0; i < 4; ++i) {
      *(float4*)&Bvec[(size_t)blk*8192 + (d1b+i)*128 + vb] =
        make_float4(bacc[i][0],bacc[i][1],bacc[i][2],bacc[i][3]);
      *(float4*)&Bvec[(size_t)blk*8192 + (d1b+i)*128 + vb + 4] =
        make_float4(bacc[i][4],bacc[i][5],bacc[i][6],bacc[i][7]);
    }
  }

  {
    #pragma unroll
    for (int i = 0; i < 32; ++i) {
      int v = w*32 + i;
      UvT[(size_t)blk*8192 + v*64 + l] = f2bu(Xv[l][v]);
    }
    #pragma unroll
    for (int i = 0; i < 16; ++i) {
      int d = w*16 + i;
      WnTb[(size_t)blk*4096 + d*64 + l] = f2bu(-Xw[l][d]);
    }
  }
}

// Phase B: h_{c+1} = D_c h_c + b_c ; 128 blocks (bh x 8 vgroups of 16)
__global__ __launch_bounds__(256) void chunkB2_k(const float* __restrict__ Dbuf,
   const float* __restrict__ Bvec, const float* __restrict__ init,
   unsigned short* __restrict__ HcT)
{
  const int blk = blockIdx.x;
  const int bh = blk >> 3, grp = blk & 7;
  const int v0 = grp*16;
  const int tid = threadIdx.x;
  const int v = tid & 15;
  const int d1b = (tid >> 4) * 4;
  __shared__ float DT[64][68];
  __shared__ float bsh[64][17];
  __shared__ float hsh[64][17];

  float hreg[4];
  #pragma unroll
  for (int j = 0; j < 4; ++j) {
    hreg[j] = init[((size_t)bh*64 + d1b + j)*128 + v0 + v];
    hsh[d1b + j][v] = hreg[j];
  }
  float Dreg[16], breg[4];
  {
    const float* Dp = Dbuf + (size_t)(bh*16)*4096;
    const float* bp = Bvec + (size_t)(bh*16)*8192;
    #pragma unroll
    for (int i = 0; i < 16; ++i) Dreg[i] = Dp[tid + i*256];
    #pragma unroll
    for (int i = 0; i < 4; ++i)  breg[i] = bp[(size_t)((tid>>4) + i*16)*128 + v0 + v];
  }
  #pragma unroll
  for (int i = 0; i < 16; ++i) {
    int cell = tid + i*256; DT[cell & 63][cell >> 6] = Dreg[i];
  }
  #pragma unroll
  for (int i = 0; i < 4; ++i) bsh[(tid>>4) + i*16][v] = breg[i];
  __syncthreads();

  for (int c = 0; c < 16; ++c) {
    if (c < 15) {
      const float* Dn = Dbuf + (size_t)(bh*16 + c + 1)*4096;
      const float* bn = Bvec + (size_t)(bh*16 + c + 1)*8192;
      #pragma unroll
      for (int i = 0; i < 16; ++i) Dreg[i] = Dn[tid + i*256];
      #pragma unroll
      for (int i = 0; i < 4; ++i)  breg[i] = bn[(size_t)((tid>>4) + i*16)*128 + v0 + v];
    }
    #pragma unroll
    for (int j = 0; j < 4; ++j)
      HcT[(size_t)(bh*16 + c)*8192 + (size_t)(v0+v)*64 + d1b + j] = f2bu(hreg[j]);
    float nh[4];
    #pragma unroll
    for (int j = 0; j < 4; ++j) nh[j] = bsh[d1b + j][v];
    #pragma unroll 8
    for (int d2 = 0; d2 < 64; ++d2) {
      float hv = hsh[d2][v];
      float4 dv = *(const float4*)&DT[d2][d1b];
      nh[0] = fmaf(dv.x, hv, nh[0]);
      nh[1] = fmaf(dv.y, hv, nh[1]);
      nh[2] = fmaf(dv.z, hv, nh[2]);
      nh[3] = fmaf(dv.w, hv, nh[3]);
    }
    __syncthreads();
    #pragma unroll
    for (int j = 0; j < 4; ++j) { hreg[j] = nh[j]; hsh[d1b + j][v] = nh[j]; }
    if (c < 15) {
      #pragma unroll
      for (int i = 0; i < 16; ++i) {
        int cell = tid + i*256; DT[cell & 63][cell >> 6] = Dreg[i];
      }
      #pragma unroll
      for (int i = 0; i < 4; ++i) bsh[(tid>>4) + i*16][v] = breg[i];
    }
    __syncthreads();
  }
}

// Phase C (MFMA): S = decayed-masked QK^T; Qt = E.Q - S Wt; o = Qt h + S U;
// fused gated RMSNorm -> ofin bf16
__global__ __launch_bounds__(256) void chunkC_k(
   const unsigned short* __restrict__ qnb, const unsigned short* __restrict__ knb,
   const unsigned short* __restrict__ UvT, const unsigned short* __restrict__ WnTb,
   const float* __restrict__ Gcbuf, const unsigned short* __restrict__ HcT,
   const unsigned short* __restrict__ Zb, const float* __restrict__ onw,
   __hip_bfloat16* __restrict__ ofin)
{
  const int blk = blockIdx.x; const int bh = blk >> 4, c = blk & 15;
  const int b = bh >> 3, h = bh & 7;
  const int row0 = b*SEQ + c*64;
  const int tid = threadIdx.x;
  const int w = tid >> 6, l = tid & 63;
  const int fr = l & 15, fq = l >> 4;

  __shared__ unsigned short Qs[64*72];
  __shared__ unsigned short Ks[64*72];
  __shared__ unsigned short Ws[64*72];
  __shared__ unsigned short hT[128*72];
  __shared__ unsigned short UT[128*72];
  __shared__ unsigned short Ss[64*72];
  __shared__ float Gsh[64], Esh[64];

  #pragma unroll
  for (int j = 0; j < 2; ++j) {
    int lin = tid + j*256; int t = lin >> 3, dq = (lin & 7)*8;
    *(uint4*)&Qs[t*72+dq] = *(const uint4*)&qnb[(size_t)(row0+t)*TKD + h*64 + dq];
    *(uint4*)&Ks[t*72+dq] = *(const uint4*)&knb[(size_t)(row0+t)*TKD + h*64 + dq];
    *(uint4*)&Ws[t*72+dq] = *(const uint4*)&WnTb[(size_t)blk*4096 + t*64 + dq];
  }
  #pragma unroll
  for (int j = 0; j < 4; ++j) {
    int lin = tid + j*256; int v = lin >> 3, dq = (lin & 7)*8;
    *(uint4*)&hT[v*72+dq] = *(const uint4*)&HcT[(size_t)blk*8192 + (size_t)v*64 + dq];
    *(uint4*)&UT[v*72+dq] = *(const uint4*)&UvT[(size_t)blk*8192 + (size_t)v*64 + dq];
  }
  if (tid < 64) { float g = Gcbuf[(size_t)blk*64 + tid]; Gsh[tid] = g; Esh[tid] = expf(g); }
  __syncthreads();

  f32x4 accS[4];
  #pragma unroll
  for (int n = 0; n < 4; ++n) accS[n] = (f32x4){0.f,0.f,0.f,0.f};
  #pragma unroll
  for (int k0 = 0; k0 < 2; ++k0) {
    bf16x8 a = *(const bf16x8*)&Qs[(w*16+fr)*72 + k0*32 + fq*8];
    #pragma unroll
    for (int n = 0; n < 4; ++n) {
      bf16x8 bb = *(const bf16x8*)&Ks[(n*16+fr)*72 + k0*32 + fq*8];
      accS[n] = __builtin_amdgcn_mfma_f32_16x16x32_bf16(a, bb, accS[n], 0, 0, 0);
    }
  }
  #pragma unroll
  for (int n = 0; n < 4; ++n)
    #pragma unroll
    for (int r = 0; r < 4; ++r) {
      int t = w*16 + fq*4 + r, s = n*16 + fr;
      float val = (s <= t) ? expf(Gsh[t]-Gsh[s]) * accS[n][r] : 0.f;
      Ss[t*72 + s] = f2bu(val);
    }

  f32x4 accQ[4];
  #pragma unroll
  for (int n = 0; n < 4; ++n) {
    #pragma unroll
    for (int r = 0; r < 4; ++r) {
      int t = w*16 + fq*4 + r, d = n*16 + fr;
      accQ[n][r] = Esh[t] * b2f(Qs[t*72 + d]);
    }
    #pragma unroll
    for (int k0 = 0; k0 < 2; ++k0) {
      bf16x8 a = *(const bf16x8*)&Ss[(w*16+fr)*72 + k0*32 + fq*8];
      bf16x8 bb = *(const bf16x8*)&Ws[(n*16+fr)*72 + k0*32 + fq*8];
      accQ[n] = __builtin_amdgcn_mfma_f32_16x16x32_bf16(a, bb, accQ[n], 0, 0, 0);
    }
  }
  __syncthreads();

  #pragma unroll
  for (int n = 0; n < 4; ++n)
    #pragma unroll
    for (int r = 0; r < 4; ++r) {
      int t = w*16 + fq*4 + r, d = n*16 + fr;
      Ks[t*72 + d] = f2bu(accQ[n][r]);
    }

  float og[8][4];
  #pragma unroll
  for (int n = 0; n < 8; ++n) {
    f32x4 acc = (f32x4){0.f,0.f,0.f,0.f};
    #pragma unroll
    for (int k0 = 0; k0 < 2; ++k0) {
      bf16x8 a1 = *(const bf16x8*)&Ks[(w*16+fr)*72 + k0*32 + fq*8];
      bf16x8 b1 = *(const bf16x8*)&hT[(n*16+fr)*72 + k0*32 + fq*8];
      acc = __builtin_amdgcn_mfma_f32_16x16x32_bf16(a1, b1, acc, 0, 0, 0);
      bf16x8 a2 = *(const bf16x8*)&Ss[(w*16+fr)*72 + k0*32 + fq*8];
      bf16x8 b2v = *(const bf16x8*)&UT[(n*16+fr)*72 + k0*32 + fq*8];
      acc = __builtin_amdgcn_mfma_f32_16x16x32_bf16(a2, b2v, acc, 0, 0, 0);
    }
    #pragma unroll
    for (int r = 0; r < 4; ++r) og[n][r] = acc[r];
  }

  float ss0 = 0.f, ss1 = 0.f, ss2 = 0.f, ss3 = 0.f;
  #pragma unroll
  for (int n = 0; n < 8; ++n) {
    #pragma unroll
    for (int r = 0; r < 4; ++r) {
      int t = w*16 + fq*4 + r, v = n*16 + fr;
      float zf = b2f(Zb[(size_t)(row0+t)*1024 + h*128 + v]);
      float g0 = og[n][r] * siluf(zf);
      og[n][r] = g0;
      float g2 = g0*g0;
      if      (r == 0) ss0 += g2;
      else if (r == 1) ss1 += g2;
      else if (r == 2) ss2 += g2;
      else             ss3 += g2;
    }
  }
  #pragma unroll
  for (int o = 1; o <= 8; o <<= 1) {
    ss0 += __shfl_xor(ss0, o); ss1 += __shfl_xor(ss1, o);
    ss2 += __shfl_xor(ss2, o); ss3 += __shfl_xor(ss3, o);
  }
  float rr[4];
  rr[0] = rsqrtf(ss0*(1.f/128.f) + 1e-6f);
  rr[1] = rsqrtf(ss1*(1.f/128.f) + 1e-6f);
  rr[2] = rsqrtf(ss2*(1.f/128.f) + 1e-6f);
  rr[3] = rsqrtf(ss3*(1.f/128.f) + 1e-6f);
  #pragma unroll
  for (int n = 0; n < 8; ++n) {
    float ow = onw[n*16 + fr];
    #pragma unroll
    for (int r = 0; r < 4; ++r) {
      int t = w*16 + fq*4 + r, v = n*16 + fr;
      ofin[(size_t)(row0+t)*1024 + h*128 + v] = __float2bfloat16(og[n][r] * rr[r] * ow);
    }
  }
}

extern "C" void kernel_launch(void* const* d_in, const int* in_sizes, int n_in,
                              void* d_out, int out_size, void* d_ws, size_t ws_size,
                              hipStream_t stream) {
  const float* hidden     = (const float*)d_in[0];
  const float* Wqkvabz    = (const float*)d_in[1];
  const float* A_log      = (const float*)d_in[2];
  const float* dt_bias    = (const float*)d_in[3];
  const float* conv_state = (const float*)d_in[4];
  const float* w1         = (const float*)d_in[5];
  const float* w2         = (const float*)d_in[6];
  const float* b2         = (const float*)d_in[7];
  const float* init_state = (const float*)d_in[8];
  const float* o_norm_w   = (const float*)d_in[9];
  const float* W_o        = (const float*)d_in[10];
  float* out = (float*)d_out;

  float* ws = (float*)d_ws;
  float* qregion = ws;                                 // qkvb lives here
  float* kern   = qregion + (size_t)6324224;
  float* zspare = kern   + (size_t)8388608;
  float* knsp   = zspare + (size_t)1048576;
  float* gbuf   = knsp   + (size_t)1048576;
  float* bbuf   = gbuf   + (size_t)16384;
  float* vconv  = bbuf   + (size_t)16384;
  float* bfpool = vconv  + (size_t)2097152;
  __hip_bfloat16* hidden_bf = (__hip_bfloat16*)bfpool;
  __hip_bfloat16* w1t   = hidden_bf + (size_t)4194304;
  __hip_bfloat16* w2t   = w1t + (size_t)262144;
  __hip_bfloat16* Wot   = w2t + (size_t)524288;
  __hip_bfloat16* x1sb  = Wot + (size_t)2097152;
  __hip_bfloat16* ofinb = x1sb + (size_t)262144;
  float* Gcbuf  = (float*)(ofinb + (size_t)2097152);
  // aliases:
  unsigned short* qkvb   = (unsigned short*)qregion;         // [2048][2048] bf16
  __hip_bfloat16* Wcat   = (__hip_bfloat16*)kern;            // [3328][2048] bf16
  __hip_bfloat16* kernbf = (__hip_bfloat16*)kern;            // w2 out
  float* Dbuf   = kern + (size_t)2097152;
  float* Bvec   = kern + (size_t)3145728;
  unsigned short* UvTb  = (unsigned short*)(kern + (size_t)5242880);
  unsigned short* WnTbb = (unsigned short*)(kern + (size_t)6291456);
  unsigned short* qnb   = (unsigned short*)(kern + (size_t)6815744);
  unsigned short* knb   = (unsigned short*)(kern + (size_t)7340032);
  unsigned short* HcTb  = (unsigned short*)vconv;
  unsigned short* zb    = (unsigned short*)zspare;

  dim3 blk(256);
  prep_k<<<13312, blk, 0, stream>>>(Wqkvabz, w1, w2, W_o, hidden,
                                    Wcat, w2t, Wot, (unsigned short*)hidden_bf);
  // fused qkvabz(all-bf16) + w1 GEMM: M=2048, N=3328, K=2048 -> 32 by x 26 bx
  mgemm_k<3><<<dim3(832),  blk, 0, stream>>>(hidden_bf, Wcat, nullptr,
      nullptr, (__hip_bfloat16*)qkvb, zb, (unsigned short*)x1sb,
      A_log, dt_bias, gbuf, bbuf, 2048, 3328, 2048, 32);
  // w2 GEMM: M=2048, N=4096, K=128 -> 32 by x 32 bx
  mgemm_k<2><<<dim3(1024), blk, 0, stream>>>(x1sb, w2t, b2,
      nullptr, kernbf, nullptr, nullptr, nullptr, nullptr, nullptr, nullptr,
      2048, 4096, 128, 32);
  // fused actv + conv (bf16 inputs)
  ac_k<<<12288, blk, 0, stream>>>(qkvb, kernbf, conv_state, qnb, knb, vconv);
  chunkA_k<<<256, blk, 0, stream>>>(knb, vconv, gbuf, bbuf, Gcbuf, Dbuf, Bvec, UvTb, WnTbb);
  chunkB2_k<<<128, blk, 0, stream>>>(Dbuf, Bvec, init_state, HcTb);
  chunkC_k<<<256, blk, 0, stream>>>(qnb, knb, UvTb, WnTbb, Gcbuf, HcTb, zb, o_norm_w, ofinb);
  // out GEMM: M=2048, N=2048, K=1024 -> 32 by x 16 bx
  mgemm_k<0><<<dim3(512),  blk, 0, stream>>>(ofinb, Wot, nullptr,
      out, nullptr, nullptr, nullptr, nullptr, nullptr, nullptr, nullptr,
      2048, 2048, 1024, 32);
}